// Round 6
// baseline (520.778 us; speedup 1.0000x reference)
//
#include <hip/hip_runtime.h>

#define BT 48
#define NN 2048
#define FF 64
#define EE 32768
#define ROWS (BT*NN)          // 98304
#define PR_ROWS 32            // rows per proj block -> 3072 blocks

// round-to-nearest-even bf16 bits of a float
__device__ __forceinline__ unsigned bf16bits(float f){
    unsigned u = __float_as_uint(f);
    return (u + 0x7fffu + ((u >> 16) & 1u)) >> 16;
}

// ---------------- Kernel 1: fused projections + QV pack ----------------
// Block = 128 threads (2 waves). Wave 0: K(a),Q(b); wave 1: V(a),skip(b).
// After each 4-row group, wave1 stages V in LDS (double-buffered), wave0
// packs QV[row][f] = (bf16(v)<<16) | bf16(q)  -> 256 B rows for agg.
__global__ __launch_bounds__(128, 2) void proj_kernel(
    const float* __restrict__ x,
    const float* __restrict__ Wk, const float* __restrict__ bk,
    const float* __restrict__ Wq, const float* __restrict__ bq,
    const float* __restrict__ Wv, const float* __restrict__ bv,
    const float* __restrict__ Ws, const float* __restrict__ bs,
    float* __restrict__ K, unsigned* __restrict__ QV,
    float* __restrict__ out)
{
    __shared__ float xs[PR_ROWS*FF];      // 8 KB
    __shared__ float vbuf[2][4][FF];      // 2 KB double-buffered V staging
    const int tid = threadIdx.x;          // 0..127
    const int w   = tid >> 6;             // wave id: 0 or 1
    const int col = tid & 63;
    const float* WA = (w==0) ? Wk : Wv;
    const float* WB = (w==0) ? Wq : Ws;
    const float bA  = (w==0) ? bk[col] : bv[col];
    const float bB  = (w==0) ? bq[col] : bs[col];

    float wA[64], wB[64];
    #pragma unroll
    for (int k=0;k<64;k++){ wA[k] = WA[k*64 + col]; wB[k] = WB[k*64 + col]; }

    const int row0 = blockIdx.x * PR_ROWS;
    const float4* xg = (const float4*)(x + (size_t)row0*FF);
    float4* xl = (float4*)xs;
    #pragma unroll
    for (int i=0;i<4;i++) xl[tid + 128*i] = xg[tid + 128*i];
    __syncthreads();

    for (int r=0; r<PR_ROWS; r+=4){
        const int buf = (r>>2) & 1;
        float a0=bA,a1=bA,a2=bA,a3=bA;
        float b0=bB,b1=bB,b2=bB,b3=bB;
        const float4* p0 = (const float4*)(xs + (r+0)*FF);
        const float4* p1 = (const float4*)(xs + (r+1)*FF);
        const float4* p2 = (const float4*)(xs + (r+2)*FF);
        const float4* p3 = (const float4*)(xs + (r+3)*FF);
        #pragma unroll
        for (int k=0;k<16;k++){
            const float4 x0 = p0[k], x1 = p1[k], x2 = p2[k], x3 = p3[k];
            a0 = fmaf(x0.x, wA[4*k+0], a0); a0 = fmaf(x0.y, wA[4*k+1], a0);
            a0 = fmaf(x0.z, wA[4*k+2], a0); a0 = fmaf(x0.w, wA[4*k+3], a0);
            b0 = fmaf(x0.x, wB[4*k+0], b0); b0 = fmaf(x0.y, wB[4*k+1], b0);
            b0 = fmaf(x0.z, wB[4*k+2], b0); b0 = fmaf(x0.w, wB[4*k+3], b0);
            a1 = fmaf(x1.x, wA[4*k+0], a1); a1 = fmaf(x1.y, wA[4*k+1], a1);
            a1 = fmaf(x1.z, wA[4*k+2], a1); a1 = fmaf(x1.w, wA[4*k+3], a1);
            b1 = fmaf(x1.x, wB[4*k+0], b1); b1 = fmaf(x1.y, wB[4*k+1], b1);
            b1 = fmaf(x1.z, wB[4*k+2], b1); b1 = fmaf(x1.w, wB[4*k+3], b1);
            a2 = fmaf(x2.x, wA[4*k+0], a2); a2 = fmaf(x2.y, wA[4*k+1], a2);
            a2 = fmaf(x2.z, wA[4*k+2], a2); a2 = fmaf(x2.w, wA[4*k+3], a2);
            b2 = fmaf(x2.x, wB[4*k+0], b2); b2 = fmaf(x2.y, wB[4*k+1], b2);
            b2 = fmaf(x2.z, wB[4*k+2], b2); b2 = fmaf(x2.w, wB[4*k+3], b2);
            a3 = fmaf(x3.x, wA[4*k+0], a3); a3 = fmaf(x3.y, wA[4*k+1], a3);
            a3 = fmaf(x3.z, wA[4*k+2], a3); a3 = fmaf(x3.w, wA[4*k+3], a3);
            b3 = fmaf(x3.x, wB[4*k+0], b3); b3 = fmaf(x3.y, wB[4*k+1], b3);
            b3 = fmaf(x3.z, wB[4*k+2], b3); b3 = fmaf(x3.w, wB[4*k+3], b3);
        }
        if (w == 1){                       // stage V for the packer
            vbuf[buf][0][col]=a0; vbuf[buf][1][col]=a1;
            vbuf[buf][2][col]=a2; vbuf[buf][3][col]=a3;
        }
        __syncthreads();
        const size_t ob = (size_t)(row0 + r)*FF + col;
        if (w == 0){
            K[ob]        = a0;  K[ob + FF]   = a1;
            K[ob + 2*FF] = a2;  K[ob + 3*FF] = a3;
            QV[ob]        = (bf16bits(vbuf[buf][0][col])<<16) | bf16bits(b0);
            QV[ob + FF]   = (bf16bits(vbuf[buf][1][col])<<16) | bf16bits(b1);
            QV[ob + 2*FF] = (bf16bits(vbuf[buf][2][col])<<16) | bf16bits(b2);
            QV[ob + 3*FF] = (bf16bits(vbuf[buf][3][col])<<16) | bf16bits(b3);
        } else {
            out[ob]        = b0;  out[ob + FF]   = b1;
            out[ob + 2*FF] = b2;  out[ob + 3*FF] = b3;
        }
    }
}

// ---------------- CSR build: 4 small parallel kernels ----------------
__global__ __launch_bounds__(256) void csr_init_kernel(
    const unsigned int* __restrict__ ew, int* __restrict__ flag, int* __restrict__ deg,
    int* __restrict__ elist)
{
    const int tid = threadIdx.x;
    if (tid == 0) *flag = 0;
    if (tid < 16) elist[EE + tid] = 0;    // pad: agg's 16-edge loop reads past s1
    for (int i=tid; i<NN; i+=256) deg[i] = 0;
    __syncthreads();
    unsigned int f = 0;
    for (int i=tid; i<8192; i+=256) f |= ew[2*i+1];
    if (f) atomicOr((unsigned int*)flag, f);
}

__global__ __launch_bounds__(256) void csr_hist_kernel(
    const unsigned int* __restrict__ ew, const int* __restrict__ flag, int* __restrict__ deg)
{
    const bool i64 = (*flag == 0);
    const int gtid = blockIdx.x*256 + threadIdx.x;   // 16384 threads
    for (int e=gtid; e<EE; e+=16384){
        const int d = i64 ? (int)ew[2*(EE+e)] : (int)ew[EE+e];
        atomicAdd(&deg[d], 1);
    }
}

__global__ __launch_bounds__(1024) void csr_scan_kernel(
    const int* __restrict__ deg, int* __restrict__ offs, int* __restrict__ cur)
{
    __shared__ int wsum[16];
    const int tid = threadIdx.x;
    const int a = deg[2*tid], b = deg[2*tid+1];
    const int s2 = a + b;
    int inc = s2;
    const int lane = tid & 63, wid = tid >> 6;
    #pragma unroll
    for (int d=1; d<64; d<<=1){ int t = __shfl_up(inc, d, 64); if (lane>=d) inc += t; }
    if (lane==63) wsum[wid] = inc;
    __syncthreads();
    if (wid==0){
        int v = (lane<16) ? wsum[lane] : 0;
        int inc2 = v;
        #pragma unroll
        for (int d=1; d<16; d<<=1){ int t = __shfl_up(inc2, d, 64); if (lane>=d) inc2 += t; }
        if (lane<16) wsum[lane] = inc2 - v;
    }
    __syncthreads();
    const int excl = wsum[wid] + (inc - s2);
    offs[2*tid]   = excl;
    offs[2*tid+1] = excl + a;
    cur[2*tid]    = excl;
    cur[2*tid+1]  = excl + a;
    if (tid==1023) offs[NN] = excl + a + b;
}

__global__ __launch_bounds__(256) void csr_place_kernel(
    const unsigned int* __restrict__ ew, const int* __restrict__ flag,
    int* __restrict__ cur, int* __restrict__ elist)
{
    const bool i64 = (*flag == 0);
    const int gtid = blockIdx.x*256 + threadIdx.x;
    for (int e=gtid; e<EE; e+=16384){
        int d, s;
        if (i64){ d = (int)ew[2*(EE+e)]; s = (int)ew[2*e]; }
        else    { d = (int)ew[EE+e];     s = (int)ew[e];   }
        const int pos = atomicAdd(&cur[d], 1);
        elist[pos] = s;
    }
}

// ---------------- Kernel 3: gather + gate + aggregate ----------------
// wave = (bt,node); sub = lane>>4 edge slot (4 edges each), fq = lane&15
// feature quad. QV packed rows: per edge ONE uint4 gather (4 lines/edge
// vs 8 for fp32 Q+V). 16 edges/iter, all 4 elist + 4 QV loads
// independent -> deg-16 nodes finish in one iteration.
// XCD-pinned: block b -> XCD b%8; each bt's 0.5MB QV slice stays in L2.
#define ACCF(uc, kc, accc) { \
    const float q_ = __uint_as_float((uc) << 16); \
    const float v_ = __uint_as_float((uc) & 0xFFFF0000u); \
    float g_ = (kc) + q_; g_ = fmaxf(g_, 0.01f*g_); \
    (accc) = fmaf(g_, v_, (accc)); }
#define ACCFM(uc, kc, accc, m) { \
    const float q_ = __uint_as_float((uc) << 16); \
    const float v_ = __uint_as_float((uc) & 0xFFFF0000u) * (m); \
    float g_ = (kc) + q_; g_ = fmaxf(g_, 0.01f*g_); \
    (accc) = fmaf(g_, v_, (accc)); }

__global__ __launch_bounds__(256) void agg_kernel(
    const float* __restrict__ K, const unsigned* __restrict__ QV,
    const int* __restrict__ offs, const int* __restrict__ elist,
    float* __restrict__ out)
{
    const int tid  = threadIdx.x;
    const int lane = tid & 63;
    const int w    = tid >> 6;
    const int b    = blockIdx.x;          // 24576 blocks
    const int xcd  = b & 7;
    const int li   = b >> 3;              // 0..3071
    const int bt   = xcd*6 + (li >> 9);   // 6 bts per XCD
    const int node = ((li & 511) << 2) | w;
    const int sub  = lane >> 4;           // edge slot 0..3 (4 edges each)
    const int fq   = lane & 15;           // feature quad 0..15
    const size_t S    = (size_t)NN*FF;
    const size_t rowb = (size_t)bt*S + (size_t)node*FF;

    const float4 kf = *(const float4*)(K + rowb + fq*4);
    const unsigned* QVb = QV + (size_t)bt*S;

    float4 acc = {0.f,0.f,0.f,0.f};
    const int s0 = offs[node], s1 = offs[node+1];

    for (int i = s0; i < s1; i += 16){
        const int rem  = s1 - i;          // wave-uniform
        const int base = i + 4*sub;
        const int e0 = elist[base+0];
        const int e1 = elist[base+1];
        const int e2 = elist[base+2];
        const int e3 = elist[base+3];
        const uint4 u0 = *(const uint4*)(QVb + (((unsigned)e0)<<6) + (fq<<2));
        const uint4 u1 = *(const uint4*)(QVb + (((unsigned)e1)<<6) + (fq<<2));
        const uint4 u2 = *(const uint4*)(QVb + (((unsigned)e2)<<6) + (fq<<2));
        const uint4 u3 = *(const uint4*)(QVb + (((unsigned)e3)<<6) + (fq<<2));
        if (rem >= 16){
            ACCF(u0.x, kf.x, acc.x); ACCF(u0.y, kf.y, acc.y);
            ACCF(u0.z, kf.z, acc.z); ACCF(u0.w, kf.w, acc.w);
            ACCF(u1.x, kf.x, acc.x); ACCF(u1.y, kf.y, acc.y);
            ACCF(u1.z, kf.z, acc.z); ACCF(u1.w, kf.w, acc.w);
            ACCF(u2.x, kf.x, acc.x); ACCF(u2.y, kf.y, acc.y);
            ACCF(u2.z, kf.z, acc.z); ACCF(u2.w, kf.w, acc.w);
            ACCF(u3.x, kf.x, acc.x); ACCF(u3.y, kf.y, acc.y);
            ACCF(u3.z, kf.z, acc.z); ACCF(u3.w, kf.w, acc.w);
        } else {
            const float m0 = (4*sub+0 < rem) ? 1.f : 0.f;
            const float m1 = (4*sub+1 < rem) ? 1.f : 0.f;
            const float m2 = (4*sub+2 < rem) ? 1.f : 0.f;
            const float m3 = (4*sub+3 < rem) ? 1.f : 0.f;
            ACCFM(u0.x, kf.x, acc.x, m0); ACCFM(u0.y, kf.y, acc.y, m0);
            ACCFM(u0.z, kf.z, acc.z, m0); ACCFM(u0.w, kf.w, acc.w, m0);
            ACCFM(u1.x, kf.x, acc.x, m1); ACCFM(u1.y, kf.y, acc.y, m1);
            ACCFM(u1.z, kf.z, acc.z, m1); ACCFM(u1.w, kf.w, acc.w, m1);
            ACCFM(u2.x, kf.x, acc.x, m2); ACCFM(u2.y, kf.y, acc.y, m2);
            ACCFM(u2.z, kf.z, acc.z, m2); ACCFM(u2.w, kf.w, acc.w, m2);
            ACCFM(u3.x, kf.x, acc.x, m3); ACCFM(u3.y, kf.y, acc.y, m3);
            ACCFM(u3.z, kf.z, acc.z, m3); ACCFM(u3.w, kf.w, acc.w, m3);
        }
    }

    // merge the 4 edge slots (lanes fq, fq+16, fq+32, fq+48)
    acc.x += __shfl_xor(acc.x, 16, 64); acc.y += __shfl_xor(acc.y, 16, 64);
    acc.z += __shfl_xor(acc.z, 16, 64); acc.w += __shfl_xor(acc.w, 16, 64);
    acc.x += __shfl_xor(acc.x, 32, 64); acc.y += __shfl_xor(acc.y, 32, 64);
    acc.z += __shfl_xor(acc.z, 32, 64); acc.w += __shfl_xor(acc.w, 32, 64);

    if (sub == 0){
        const float4 sk = *(const float4*)(out + rowb + fq*4);  // skip+bias
        float4 r;
        r.x = acc.x + sk.x; r.y = acc.y + sk.y;
        r.z = acc.z + sk.z; r.w = acc.w + sk.w;
        *(float4*)(out + rowb + fq*4) = r;
    }
}

extern "C" void kernel_launch(void* const* d_in, const int* in_sizes, int n_in,
                              void* d_out, int out_size, void* d_ws, size_t ws_size,
                              hipStream_t stream)
{
    const float* x  = (const float*)d_in[0];
    const unsigned int* ew = (const unsigned int*)d_in[1];
    const float* Wk = (const float*)d_in[2];
    const float* bk = (const float*)d_in[3];
    const float* Wq = (const float*)d_in[4];
    const float* bq = (const float*)d_in[5];
    const float* Wv = (const float*)d_in[6];
    const float* bv = (const float*)d_in[7];
    const float* Ws = (const float*)d_in[8];
    const float* bs = (const float*)d_in[9];
    float* out = (float*)d_out;

    float* K = (float*)d_ws;
    const size_t n = (size_t)ROWS*FF;
    unsigned* QV = (unsigned*)(K + n);
    int* meta  = (int*)(QV + n);
    int* flag  = meta;
    int* deg   = meta + 16;
    int* offs  = deg + NN;
    int* cur   = offs + NN + 16;
    int* elist = cur + NN;

    hipLaunchKernelGGL(proj_kernel, dim3(ROWS/PR_ROWS), dim3(128), 0, stream,
                       x, Wk,bk, Wq,bq, Wv,bv, Ws,bs, K, QV, out);
    hipLaunchKernelGGL(csr_init_kernel,  dim3(1),  dim3(256),  0, stream, ew, flag, deg, elist);
    hipLaunchKernelGGL(csr_hist_kernel,  dim3(64), dim3(256),  0, stream, ew, flag, deg);
    hipLaunchKernelGGL(csr_scan_kernel,  dim3(1),  dim3(1024), 0, stream, deg, offs, cur);
    hipLaunchKernelGGL(csr_place_kernel, dim3(64), dim3(256),  0, stream, ew, flag, cur, elist);
    hipLaunchKernelGGL(agg_kernel, dim3(ROWS/4), dim3(256), 0, stream,
                       K, QV, offs, elist, out);
}

// Round 7
// 126.029 us; speedup vs baseline: 4.1322x; 4.1322x over previous
//
#include <hip/hip_runtime.h>

#define BT 48
#define NN 2048
#define FF 64
#define EE 32768
#define ROWS (BT*NN)          // 98304
#define PR_ROWS 32            // rows per proj block -> 3072 blocks

// round-to-nearest-even bf16 bits of a float
__device__ __forceinline__ unsigned bf16bits(float f){
    unsigned u = __float_as_uint(f);
    return (u + 0x7fffu + ((u >> 16) & 1u)) >> 16;
}

// ---------------- Kernel 1: fused projections + QV pack ----------------
// Block = 256 threads (4 waves): wave 0->K, 1->Q, 2->V, 3->skip. One weight
// matrix per wave (w[64] = 64 VGPRs -> no spill; R6's 2-matrix version
// spilled to scratch, 1.3GB of HBM traffic). V-wave stages 4-row results in
// LDS (double-buffered); Q-wave packs QV[row][f] = (bf16(v)<<16)|bf16(q).
__global__ __launch_bounds__(256) void proj_kernel(
    const float* __restrict__ x,
    const float* __restrict__ Wk, const float* __restrict__ bk,
    const float* __restrict__ Wq, const float* __restrict__ bq,
    const float* __restrict__ Wv, const float* __restrict__ bv,
    const float* __restrict__ Ws, const float* __restrict__ bs,
    float* __restrict__ K, unsigned* __restrict__ QV,
    float* __restrict__ out)
{
    __shared__ float xs[PR_ROWS*FF];      // 8 KB
    __shared__ float vbuf[2][4][FF];      // 2 KB double-buffered V staging
    const int tid = threadIdx.x;          // 0..255
    const int w   = tid >> 6;             // wave id: 0..3
    const int col = tid & 63;
    const float* Wm = (w==0)?Wk:(w==1)?Wq:(w==2)?Wv:Ws;
    const float* bm = (w==0)?bk:(w==1)?bq:(w==2)?bv:bs;

    float wr[64];
    #pragma unroll
    for (int k=0;k<64;k++) wr[k] = Wm[k*64 + col];
    const float bias = bm[col];

    const int row0 = blockIdx.x * PR_ROWS;
    const float4* xg = (const float4*)(x + (size_t)row0*FF);
    float4* xl = (float4*)xs;
    xl[tid]       = xg[tid];
    xl[tid + 256] = xg[tid + 256];
    __syncthreads();

    for (int r=0; r<PR_ROWS; r+=4){
        const int buf = (r>>2) & 1;
        float a0=bias,a1=bias,a2=bias,a3=bias;
        const float4* p0 = (const float4*)(xs + (r+0)*FF);
        const float4* p1 = (const float4*)(xs + (r+1)*FF);
        const float4* p2 = (const float4*)(xs + (r+2)*FF);
        const float4* p3 = (const float4*)(xs + (r+3)*FF);
        #pragma unroll
        for (int k=0;k<16;k++){
            const float4 x0 = p0[k], x1 = p1[k], x2 = p2[k], x3 = p3[k];
            a0 = fmaf(x0.x, wr[4*k+0], a0); a0 = fmaf(x0.y, wr[4*k+1], a0);
            a0 = fmaf(x0.z, wr[4*k+2], a0); a0 = fmaf(x0.w, wr[4*k+3], a0);
            a1 = fmaf(x1.x, wr[4*k+0], a1); a1 = fmaf(x1.y, wr[4*k+1], a1);
            a1 = fmaf(x1.z, wr[4*k+2], a1); a1 = fmaf(x1.w, wr[4*k+3], a1);
            a2 = fmaf(x2.x, wr[4*k+0], a2); a2 = fmaf(x2.y, wr[4*k+1], a2);
            a2 = fmaf(x2.z, wr[4*k+2], a2); a2 = fmaf(x2.w, wr[4*k+3], a2);
            a3 = fmaf(x3.x, wr[4*k+0], a3); a3 = fmaf(x3.y, wr[4*k+1], a3);
            a3 = fmaf(x3.z, wr[4*k+2], a3); a3 = fmaf(x3.w, wr[4*k+3], a3);
        }
        if (w == 2){                       // V wave stages for the packer
            vbuf[buf][0][col]=a0; vbuf[buf][1][col]=a1;
            vbuf[buf][2][col]=a2; vbuf[buf][3][col]=a3;
        }
        __syncthreads();
        const size_t ob = (size_t)(row0 + r)*FF + col;
        if (w == 0){
            K[ob]        = a0;  K[ob + FF]   = a1;
            K[ob + 2*FF] = a2;  K[ob + 3*FF] = a3;
        } else if (w == 1){                // Q wave packs QV
            QV[ob]        = (bf16bits(vbuf[buf][0][col])<<16) | bf16bits(a0);
            QV[ob + FF]   = (bf16bits(vbuf[buf][1][col])<<16) | bf16bits(a1);
            QV[ob + 2*FF] = (bf16bits(vbuf[buf][2][col])<<16) | bf16bits(a2);
            QV[ob + 3*FF] = (bf16bits(vbuf[buf][3][col])<<16) | bf16bits(a3);
        } else if (w == 3){
            out[ob]        = a0;  out[ob + FF]   = a1;
            out[ob + 2*FF] = a2;  out[ob + 3*FF] = a3;
        }
    }
}

// ---------------- CSR build: 4 small parallel kernels ----------------
__global__ __launch_bounds__(256) void csr_init_kernel(
    const unsigned int* __restrict__ ew, int* __restrict__ flag, int* __restrict__ deg,
    int* __restrict__ elist)
{
    const int tid = threadIdx.x;
    if (tid == 0) *flag = 0;
    if (tid < 16) elist[EE + tid] = 0;    // pad: agg's 16-edge loop reads past s1
    for (int i=tid; i<NN; i+=256) deg[i] = 0;
    __syncthreads();
    unsigned int f = 0;
    for (int i=tid; i<8192; i+=256) f |= ew[2*i+1];
    if (f) atomicOr((unsigned int*)flag, f);
}

__global__ __launch_bounds__(256) void csr_hist_kernel(
    const unsigned int* __restrict__ ew, const int* __restrict__ flag, int* __restrict__ deg)
{
    const bool i64 = (*flag == 0);
    const int gtid = blockIdx.x*256 + threadIdx.x;   // 16384 threads
    for (int e=gtid; e<EE; e+=16384){
        const int d = i64 ? (int)ew[2*(EE+e)] : (int)ew[EE+e];
        atomicAdd(&deg[d], 1);
    }
}

__global__ __launch_bounds__(1024) void csr_scan_kernel(
    const int* __restrict__ deg, int* __restrict__ offs, int* __restrict__ cur)
{
    __shared__ int wsum[16];
    const int tid = threadIdx.x;
    const int a = deg[2*tid], b = deg[2*tid+1];
    const int s2 = a + b;
    int inc = s2;
    const int lane = tid & 63, wid = tid >> 6;
    #pragma unroll
    for (int d=1; d<64; d<<=1){ int t = __shfl_up(inc, d, 64); if (lane>=d) inc += t; }
    if (lane==63) wsum[wid] = inc;
    __syncthreads();
    if (wid==0){
        int v = (lane<16) ? wsum[lane] : 0;
        int inc2 = v;
        #pragma unroll
        for (int d=1; d<16; d<<=1){ int t = __shfl_up(inc2, d, 64); if (lane>=d) inc2 += t; }
        if (lane<16) wsum[lane] = inc2 - v;
    }
    __syncthreads();
    const int excl = wsum[wid] + (inc - s2);
    offs[2*tid]   = excl;
    offs[2*tid+1] = excl + a;
    cur[2*tid]    = excl;
    cur[2*tid+1]  = excl + a;
    if (tid==1023) offs[NN] = excl + a + b;
}

__global__ __launch_bounds__(256) void csr_place_kernel(
    const unsigned int* __restrict__ ew, const int* __restrict__ flag,
    int* __restrict__ cur, int* __restrict__ elist)
{
    const bool i64 = (*flag == 0);
    const int gtid = blockIdx.x*256 + threadIdx.x;
    for (int e=gtid; e<EE; e+=16384){
        int d, s;
        if (i64){ d = (int)ew[2*(EE+e)]; s = (int)ew[2*e]; }
        else    { d = (int)ew[EE+e];     s = (int)ew[e];   }
        const int pos = atomicAdd(&cur[d], 1);
        elist[pos] = s;
    }
}

// ---------------- Kernel 3: gather + gate + aggregate ----------------
// wave = (bt,node); sub = lane>>4 edge slot (4 edges each), fq = lane&15
// feature quad. QV packed rows: per edge ONE uint4 gather (4 lines/edge
// vs 8 for fp32 Q+V). 16 edges/iter. XCD-pinned: block b -> XCD b%8;
// each bt's 0.5MB QV slice stays in that XCD's L2.
#define ACCF(uc, kc, accc) { \
    const float q_ = __uint_as_float((uc) << 16); \
    const float v_ = __uint_as_float((uc) & 0xFFFF0000u); \
    float g_ = (kc) + q_; g_ = fmaxf(g_, 0.01f*g_); \
    (accc) = fmaf(g_, v_, (accc)); }
#define ACCFM(uc, kc, accc, m) { \
    const float q_ = __uint_as_float((uc) << 16); \
    const float v_ = __uint_as_float((uc) & 0xFFFF0000u) * (m); \
    float g_ = (kc) + q_; g_ = fmaxf(g_, 0.01f*g_); \
    (accc) = fmaf(g_, v_, (accc)); }

__global__ __launch_bounds__(256) void agg_kernel(
    const float* __restrict__ K, const unsigned* __restrict__ QV,
    const int* __restrict__ offs, const int* __restrict__ elist,
    float* __restrict__ out)
{
    const int tid  = threadIdx.x;
    const int lane = tid & 63;
    const int w    = tid >> 6;
    const int b    = blockIdx.x;          // 24576 blocks
    const int xcd  = b & 7;
    const int li   = b >> 3;              // 0..3071
    const int bt   = xcd*6 + (li >> 9);   // 6 bts per XCD
    const int node = ((li & 511) << 2) | w;
    const int sub  = lane >> 4;           // edge slot 0..3 (4 edges each)
    const int fq   = lane & 15;           // feature quad 0..15
    const size_t S    = (size_t)NN*FF;
    const size_t rowb = (size_t)bt*S + (size_t)node*FF;

    const float4 kf = *(const float4*)(K + rowb + fq*4);
    const unsigned* QVb = QV + (size_t)bt*S;

    float4 acc = {0.f,0.f,0.f,0.f};
    const int s0 = offs[node], s1 = offs[node+1];

    for (int i = s0; i < s1; i += 16){
        const int rem  = s1 - i;          // wave-uniform
        const int base = i + 4*sub;
        const int e0 = elist[base+0];
        const int e1 = elist[base+1];
        const int e2 = elist[base+2];
        const int e3 = elist[base+3];
        const uint4 u0 = *(const uint4*)(QVb + (((unsigned)e0)<<6) + (fq<<2));
        const uint4 u1 = *(const uint4*)(QVb + (((unsigned)e1)<<6) + (fq<<2));
        const uint4 u2 = *(const uint4*)(QVb + (((unsigned)e2)<<6) + (fq<<2));
        const uint4 u3 = *(const uint4*)(QVb + (((unsigned)e3)<<6) + (fq<<2));
        if (rem >= 16){
            ACCF(u0.x, kf.x, acc.x); ACCF(u0.y, kf.y, acc.y);
            ACCF(u0.z, kf.z, acc.z); ACCF(u0.w, kf.w, acc.w);
            ACCF(u1.x, kf.x, acc.x); ACCF(u1.y, kf.y, acc.y);
            ACCF(u1.z, kf.z, acc.z); ACCF(u1.w, kf.w, acc.w);
            ACCF(u2.x, kf.x, acc.x); ACCF(u2.y, kf.y, acc.y);
            ACCF(u2.z, kf.z, acc.z); ACCF(u2.w, kf.w, acc.w);
            ACCF(u3.x, kf.x, acc.x); ACCF(u3.y, kf.y, acc.y);
            ACCF(u3.z, kf.z, acc.z); ACCF(u3.w, kf.w, acc.w);
        } else {
            const float m0 = (4*sub+0 < rem) ? 1.f : 0.f;
            const float m1 = (4*sub+1 < rem) ? 1.f : 0.f;
            const float m2 = (4*sub+2 < rem) ? 1.f : 0.f;
            const float m3 = (4*sub+3 < rem) ? 1.f : 0.f;
            ACCFM(u0.x, kf.x, acc.x, m0); ACCFM(u0.y, kf.y, acc.y, m0);
            ACCFM(u0.z, kf.z, acc.z, m0); ACCFM(u0.w, kf.w, acc.w, m0);
            ACCFM(u1.x, kf.x, acc.x, m1); ACCFM(u1.y, kf.y, acc.y, m1);
            ACCFM(u1.z, kf.z, acc.z, m1); ACCFM(u1.w, kf.w, acc.w, m1);
            ACCFM(u2.x, kf.x, acc.x, m2); ACCFM(u2.y, kf.y, acc.y, m2);
            ACCFM(u2.z, kf.z, acc.z, m2); ACCFM(u2.w, kf.w, acc.w, m2);
            ACCFM(u3.x, kf.x, acc.x, m3); ACCFM(u3.y, kf.y, acc.y, m3);
            ACCFM(u3.z, kf.z, acc.z, m3); ACCFM(u3.w, kf.w, acc.w, m3);
        }
    }

    // merge the 4 edge slots (lanes fq, fq+16, fq+32, fq+48)
    acc.x += __shfl_xor(acc.x, 16, 64); acc.y += __shfl_xor(acc.y, 16, 64);
    acc.z += __shfl_xor(acc.z, 16, 64); acc.w += __shfl_xor(acc.w, 16, 64);
    acc.x += __shfl_xor(acc.x, 32, 64); acc.y += __shfl_xor(acc.y, 32, 64);
    acc.z += __shfl_xor(acc.z, 32, 64); acc.w += __shfl_xor(acc.w, 32, 64);

    if (sub == 0){
        const float4 sk = *(const float4*)(out + rowb + fq*4);  // skip+bias
        float4 r;
        r.x = acc.x + sk.x; r.y = acc.y + sk.y;
        r.z = acc.z + sk.z; r.w = acc.w + sk.w;
        *(float4*)(out + rowb + fq*4) = r;
    }
}

extern "C" void kernel_launch(void* const* d_in, const int* in_sizes, int n_in,
                              void* d_out, int out_size, void* d_ws, size_t ws_size,
                              hipStream_t stream)
{
    const float* x  = (const float*)d_in[0];
    const unsigned int* ew = (const unsigned int*)d_in[1];
    const float* Wk = (const float*)d_in[2];
    const float* bk = (const float*)d_in[3];
    const float* Wq = (const float*)d_in[4];
    const float* bq = (const float*)d_in[5];
    const float* Wv = (const float*)d_in[6];
    const float* bv = (const float*)d_in[7];
    const float* Ws = (const float*)d_in[8];
    const float* bs = (const float*)d_in[9];
    float* out = (float*)d_out;

    float* K = (float*)d_ws;
    const size_t n = (size_t)ROWS*FF;
    unsigned* QV = (unsigned*)(K + n);
    int* meta  = (int*)(QV + n);
    int* flag  = meta;
    int* deg   = meta + 16;
    int* offs  = deg + NN;
    int* cur   = offs + NN + 16;
    int* elist = cur + NN;

    hipLaunchKernelGGL(proj_kernel, dim3(ROWS/PR_ROWS), dim3(256), 0, stream,
                       x, Wk,bk, Wq,bq, Wv,bv, Ws,bs, K, QV, out);
    hipLaunchKernelGGL(csr_init_kernel,  dim3(1),  dim3(256),  0, stream, ew, flag, deg, elist);
    hipLaunchKernelGGL(csr_hist_kernel,  dim3(64), dim3(256),  0, stream, ew, flag, deg);
    hipLaunchKernelGGL(csr_scan_kernel,  dim3(1),  dim3(1024), 0, stream, deg, offs, cur);
    hipLaunchKernelGGL(csr_place_kernel, dim3(64), dim3(256),  0, stream, ew, flag, cur, elist);
    hipLaunchKernelGGL(agg_kernel, dim3(ROWS/4), dim3(256), 0, stream,
                       K, QV, offs, elist, out);
}

// Round 8
// 111.882 us; speedup vs baseline: 4.6547x; 1.1264x over previous
//
#include <hip/hip_runtime.h>
#include <hip/hip_bf16.h>

#define BT 48
#define NN 2048
#define FF 64
#define EE 32768
#define ROWS (BT*NN)          // 98304

typedef __attribute__((ext_vector_type(8))) short short8v;
typedef __attribute__((ext_vector_type(4))) float float4v;

// v_cvt_pk_bf16_f32: lo -> low 16 bits, hi -> high 16 bits (RNE)
__device__ __forceinline__ unsigned cvt2(float lo, float hi){
    __hip_bfloat162 h = __float22bfloat162_rn(make_float2(lo, hi));
    union { __hip_bfloat162 h; unsigned u; } c; c.h = h; return c.u;
}

// ---------------- Kernel 1: MFMA projections + QV pack ----------------
// Block = 256 thr (4 waves), 64 rows. Wave w owns matrix w (0:K 1:Q 2:V
// 3:skip): full 64x64 output = 4 row-tiles x 4 col-tiles of 16x16x32 bf16
// MFMA (2 per tile for K=64). A-frags: 8 contiguous fp32 from x ->
// cvt_pk bf16 (layout: row=lane&15, k=(lane>>4)*8+j). B-frags gathered
// from W (k=(lane>>4)*8+j, col=lane&15; 64 scalar loads, L2-hot).
// D layout: row=(lane>>4)*4+j, col=lane&15 (m89-verified).
// V wave stages its tiles in LDS; Q wave packs QV=(bf16(v)<<16)|bf16(q).
__global__ __launch_bounds__(256) void proj_kernel(
    const float* __restrict__ x,
    const float* __restrict__ Wk, const float* __restrict__ bk,
    const float* __restrict__ Wq, const float* __restrict__ bq,
    const float* __restrict__ Wv, const float* __restrict__ bv,
    const float* __restrict__ Ws, const float* __restrict__ bs,
    float* __restrict__ K, unsigned* __restrict__ QV,
    float* __restrict__ out)
{
    __shared__ float vb[64][65];          // V exchange, +1 pad vs bank conflict
    const int tid = threadIdx.x;
    const int w  = tid >> 6;              // wave -> matrix
    const int l  = tid & 63;
    const int lr = l & 15;                // row (A) / col (B,D) within tile
    const int lh = l >> 4;                // k-group / row-group
    const float* Wm = (w==0)?Wk:(w==1)?Wq:(w==2)?Wv:Ws;
    const float* bm = (w==0)?bk:(w==1)?bq:(w==2)?bv:bs;

    union Frag { unsigned u[4]; short8v s; };

    // B frags: bf[c][h] = Wm[h*32 + lh*8 + j][c*16 + lr], j=0..7
    Frag bf[4][2];
    #pragma unroll
    for (int c=0;c<4;c++){
        #pragma unroll
        for (int h=0;h<2;h++){
            #pragma unroll
            for (int jj=0;jj<4;jj++){
                const int k0 = h*32 + lh*8 + 2*jj;
                const float w0 = Wm[(size_t)k0*FF     + c*16 + lr];
                const float w1 = Wm[(size_t)(k0+1)*FF + c*16 + lr];
                bf[c][h].u[jj] = cvt2(w0, w1);
            }
        }
    }

    float4v acc[4][4];                    // [col-tile][row-tile]
    #pragma unroll
    for (int c=0;c<4;c++){
        const float bias = bm[c*16 + lr];
        #pragma unroll
        for (int rt=0;rt<4;rt++) acc[c][rt] = float4v{bias,bias,bias,bias};
    }

    const int row0 = blockIdx.x * 64;
    #pragma unroll
    for (int rt=0;rt<4;rt++){
        const float* xr = x + (size_t)(row0 + rt*16 + lr)*FF + lh*8;
        const float4 xa0 = *(const float4*)(xr);
        const float4 xa1 = *(const float4*)(xr + 4);
        const float4 xb0 = *(const float4*)(xr + 32);
        const float4 xb1 = *(const float4*)(xr + 36);
        Frag a0, a1;
        a0.u[0]=cvt2(xa0.x,xa0.y); a0.u[1]=cvt2(xa0.z,xa0.w);
        a0.u[2]=cvt2(xa1.x,xa1.y); a0.u[3]=cvt2(xa1.z,xa1.w);
        a1.u[0]=cvt2(xb0.x,xb0.y); a1.u[1]=cvt2(xb0.z,xb0.w);
        a1.u[2]=cvt2(xb1.x,xb1.y); a1.u[3]=cvt2(xb1.z,xb1.w);
        #pragma unroll
        for (int c=0;c<4;c++){
            acc[c][rt] = __builtin_amdgcn_mfma_f32_16x16x32_bf16(a0.s, bf[c][0].s, acc[c][rt], 0,0,0);
            acc[c][rt] = __builtin_amdgcn_mfma_f32_16x16x32_bf16(a1.s, bf[c][1].s, acc[c][rt], 0,0,0);
        }
    }

    if (w == 2){                          // V wave -> LDS for the packer
        #pragma unroll
        for (int c=0;c<4;c++)
            #pragma unroll
            for (int rt=0;rt<4;rt++)
                #pragma unroll
                for (int j=0;j<4;j++)
                    vb[rt*16 + lh*4 + j][c*16 + lr] = acc[c][rt][j];
    }
    __syncthreads();

    if (w == 0){
        #pragma unroll
        for (int c=0;c<4;c++)
            #pragma unroll
            for (int rt=0;rt<4;rt++)
                #pragma unroll
                for (int j=0;j<4;j++)
                    K[(size_t)(row0 + rt*16 + lh*4 + j)*FF + c*16 + lr] = acc[c][rt][j];
    } else if (w == 1){                   // Q wave packs QV
        #pragma unroll
        for (int c=0;c<4;c++)
            #pragma unroll
            for (int rt=0;rt<4;rt++)
                #pragma unroll
                for (int j=0;j<4;j++){
                    const int row = rt*16 + lh*4 + j, col = c*16 + lr;
                    QV[(size_t)(row0 + row)*FF + col] = cvt2(acc[c][rt][j], vb[row][col]);
                }
    } else if (w == 3){
        #pragma unroll
        for (int c=0;c<4;c++)
            #pragma unroll
            for (int rt=0;rt<4;rt++)
                #pragma unroll
                for (int j=0;j<4;j++)
                    out[(size_t)(row0 + rt*16 + lh*4 + j)*FF + c*16 + lr] = acc[c][rt][j];
    }
}

// ---------------- Kernel 2: fused CSR build (64 blocks, spin barriers) ----
// bar[0..2] + flag zeroed by a hipMemsetAsync node before this kernel each
// launch (d_ws is NOT re-poisoned between replays, so no cross-call state).
// 64 blocks << 256 CUs -> co-residency guaranteed; graph is a linear chain
// so no other kernel occupies the device concurrently.
__device__ __forceinline__ void gbar(int* ctr, int nblk){
    __syncthreads();
    if (threadIdx.x == 0){
        __threadfence();                  // release my writes
        atomicAdd(ctr, 1);
        while (__hip_atomic_load(ctr, __ATOMIC_ACQUIRE, __HIP_MEMORY_SCOPE_AGENT) < nblk) {}
    }
    __syncthreads();
}

__global__ __launch_bounds__(256) void csr_kernel(
    const unsigned int* __restrict__ ew,
    int* __restrict__ flag, int* __restrict__ bar,
    int* __restrict__ deg, int* __restrict__ offs,
    int* __restrict__ cur, int* __restrict__ elist)
{
    const int t = threadIdx.x, b = blockIdx.x;
    const int gtid = b*256 + t;           // 16384 threads

    // P0: zero deg, pad elist, detect int64-vs-int32
    for (int i=gtid; i<NN; i+=16384) deg[i] = 0;
    if (gtid < 16) elist[EE + gtid] = 0;
    unsigned f = 0;
    for (int i=gtid; i<8192; i+=16384) f |= ew[2*i+1];
    if (f) atomicOr((unsigned int*)flag, f);
    gbar(bar+0, 64);
    const bool i64 = (*flag == 0);

    // P1: histogram of dst
    for (int e=gtid; e<EE; e+=16384){
        const int d = i64 ? (int)ew[2*(EE+e)] : (int)ew[EE+e];
        atomicAdd(&deg[d], 1);
    }
    gbar(bar+1, 64);

    // P2: exclusive scan (block 0 only; 256 thr x 8 elems)
    if (b == 0){
        __shared__ int wsums[4];
        const int base = t*8;
        int v[8], pre[8];
        #pragma unroll
        for (int j=0;j<8;j++) v[j] = deg[base+j];
        pre[0] = 0;
        #pragma unroll
        for (int j=1;j<8;j++) pre[j] = pre[j-1] + v[j-1];
        const int s = pre[7] + v[7];
        int inc = s;
        const int lane = t & 63, wid = t >> 6;
        #pragma unroll
        for (int d=1; d<64; d<<=1){ int tt = __shfl_up(inc, d, 64); if (lane>=d) inc += tt; }
        if (lane == 63) wsums[wid] = inc;
        __syncthreads();
        if (t == 0){ int a=0; for (int k2=0;k2<4;k2++){ int tt=wsums[k2]; wsums[k2]=a; a+=tt; } }
        __syncthreads();
        const int excl = wsums[wid] + (inc - s);
        #pragma unroll
        for (int j=0;j<8;j++){ offs[base+j] = excl + pre[j]; cur[base+j] = excl + pre[j]; }
        if (t == 255) offs[NN] = excl + s;  // = EE
    }
    gbar(bar+2, 64);

    // P3: place src into per-dst buckets
    for (int e=gtid; e<EE; e+=16384){
        int d, s;
        if (i64){ d = (int)ew[2*(EE+e)]; s = (int)ew[2*e]; }
        else    { d = (int)ew[EE+e];     s = (int)ew[e];   }
        const int pos = atomicAdd(&cur[d], 1);
        elist[pos] = s;
    }
}

// ---------------- Kernel 3: gather + gate + aggregate ----------------
// (unchanged from R7: QV-packed, 4 lines/edge, XCD-pinned bt groups)
#define ACCF(uc, kc, accc) { \
    const float q_ = __uint_as_float((uc) << 16); \
    const float v_ = __uint_as_float((uc) & 0xFFFF0000u); \
    float g_ = (kc) + q_; g_ = fmaxf(g_, 0.01f*g_); \
    (accc) = fmaf(g_, v_, (accc)); }
#define ACCFM(uc, kc, accc, m) { \
    const float q_ = __uint_as_float((uc) << 16); \
    const float v_ = __uint_as_float((uc) & 0xFFFF0000u) * (m); \
    float g_ = (kc) + q_; g_ = fmaxf(g_, 0.01f*g_); \
    (accc) = fmaf(g_, v_, (accc)); }

__global__ __launch_bounds__(256) void agg_kernel(
    const float* __restrict__ K, const unsigned* __restrict__ QV,
    const int* __restrict__ offs, const int* __restrict__ elist,
    float* __restrict__ out)
{
    const int tid  = threadIdx.x;
    const int lane = tid & 63;
    const int w    = tid >> 6;
    const int b    = blockIdx.x;          // 24576 blocks
    const int xcd  = b & 7;
    const int li   = b >> 3;              // 0..3071
    const int bt   = xcd*6 + (li >> 9);   // 6 bts per XCD
    const int node = ((li & 511) << 2) | w;
    const int sub  = lane >> 4;           // edge slot 0..3 (4 edges each)
    const int fq   = lane & 15;           // feature quad 0..15
    const size_t S    = (size_t)NN*FF;
    const size_t rowb = (size_t)bt*S + (size_t)node*FF;

    const float4 kf = *(const float4*)(K + rowb + fq*4);
    const unsigned* QVb = QV + (size_t)bt*S;

    float4 acc = {0.f,0.f,0.f,0.f};
    const int s0 = offs[node], s1 = offs[node+1];

    for (int i = s0; i < s1; i += 16){
        const int rem  = s1 - i;          // wave-uniform
        const int base = i + 4*sub;
        const int e0 = elist[base+0];
        const int e1 = elist[base+1];
        const int e2 = elist[base+2];
        const int e3 = elist[base+3];
        const uint4 u0 = *(const uint4*)(QVb + (((unsigned)e0)<<6) + (fq<<2));
        const uint4 u1 = *(const uint4*)(QVb + (((unsigned)e1)<<6) + (fq<<2));
        const uint4 u2 = *(const uint4*)(QVb + (((unsigned)e2)<<6) + (fq<<2));
        const uint4 u3 = *(const uint4*)(QVb + (((unsigned)e3)<<6) + (fq<<2));
        if (rem >= 16){
            ACCF(u0.x, kf.x, acc.x); ACCF(u0.y, kf.y, acc.y);
            ACCF(u0.z, kf.z, acc.z); ACCF(u0.w, kf.w, acc.w);
            ACCF(u1.x, kf.x, acc.x); ACCF(u1.y, kf.y, acc.y);
            ACCF(u1.z, kf.z, acc.z); ACCF(u1.w, kf.w, acc.w);
            ACCF(u2.x, kf.x, acc.x); ACCF(u2.y, kf.y, acc.y);
            ACCF(u2.z, kf.z, acc.z); ACCF(u2.w, kf.w, acc.w);
            ACCF(u3.x, kf.x, acc.x); ACCF(u3.y, kf.y, acc.y);
            ACCF(u3.z, kf.z, acc.z); ACCF(u3.w, kf.w, acc.w);
        } else {
            const float m0 = (4*sub+0 < rem) ? 1.f : 0.f;
            const float m1 = (4*sub+1 < rem) ? 1.f : 0.f;
            const float m2 = (4*sub+2 < rem) ? 1.f : 0.f;
            const float m3 = (4*sub+3 < rem) ? 1.f : 0.f;
            ACCFM(u0.x, kf.x, acc.x, m0); ACCFM(u0.y, kf.y, acc.y, m0);
            ACCFM(u0.z, kf.z, acc.z, m0); ACCFM(u0.w, kf.w, acc.w, m0);
            ACCFM(u1.x, kf.x, acc.x, m1); ACCFM(u1.y, kf.y, acc.y, m1);
            ACCFM(u1.z, kf.z, acc.z, m1); ACCFM(u1.w, kf.w, acc.w, m1);
            ACCFM(u2.x, kf.x, acc.x, m2); ACCFM(u2.y, kf.y, acc.y, m2);
            ACCFM(u2.z, kf.z, acc.z, m2); ACCFM(u2.w, kf.w, acc.w, m2);
            ACCFM(u3.x, kf.x, acc.x, m3); ACCFM(u3.y, kf.y, acc.y, m3);
            ACCFM(u3.z, kf.z, acc.z, m3); ACCFM(u3.w, kf.w, acc.w, m3);
        }
    }

    // merge the 4 edge slots (lanes fq, fq+16, fq+32, fq+48)
    acc.x += __shfl_xor(acc.x, 16, 64); acc.y += __shfl_xor(acc.y, 16, 64);
    acc.z += __shfl_xor(acc.z, 16, 64); acc.w += __shfl_xor(acc.w, 16, 64);
    acc.x += __shfl_xor(acc.x, 32, 64); acc.y += __shfl_xor(acc.y, 32, 64);
    acc.z += __shfl_xor(acc.z, 32, 64); acc.w += __shfl_xor(acc.w, 32, 64);

    if (sub == 0){
        const float4 sk = *(const float4*)(out + rowb + fq*4);  // skip+bias
        float4 r;
        r.x = acc.x + sk.x; r.y = acc.y + sk.y;
        r.z = acc.z + sk.z; r.w = acc.w + sk.w;
        *(float4*)(out + rowb + fq*4) = r;
    }
}

extern "C" void kernel_launch(void* const* d_in, const int* in_sizes, int n_in,
                              void* d_out, int out_size, void* d_ws, size_t ws_size,
                              hipStream_t stream)
{
    const float* x  = (const float*)d_in[0];
    const unsigned int* ew = (const unsigned int*)d_in[1];
    const float* Wk = (const float*)d_in[2];
    const float* bk = (const float*)d_in[3];
    const float* Wq = (const float*)d_in[4];
    const float* bq = (const float*)d_in[5];
    const float* Wv = (const float*)d_in[6];
    const float* bv = (const float*)d_in[7];
    const float* Ws = (const float*)d_in[8];
    const float* bs = (const float*)d_in[9];
    float* out = (float*)d_out;

    float* K = (float*)d_ws;
    const size_t n = (size_t)ROWS*FF;
    unsigned* QV = (unsigned*)(K + n);
    int* meta  = (int*)(QV + n);
    int* flag  = meta;                    // meta[0]
    int* bar   = meta + 4;                // meta[4..6]
    int* deg   = meta + 16;
    int* offs  = deg + NN;
    int* cur   = offs + NN + 16;
    int* elist = cur + NN;

    hipMemsetAsync(meta, 0, 32, stream);  // flag + bar zeroed each launch

    hipLaunchKernelGGL(proj_kernel, dim3(ROWS/64), dim3(256), 0, stream,
                       x, Wk,bk, Wq,bq, Wv,bv, Ws,bs, K, QV, out);
    hipLaunchKernelGGL(csr_kernel, dim3(64), dim3(256), 0, stream,
                       ew, flag, bar, deg, offs, cur, elist);
    hipLaunchKernelGGL(agg_kernel, dim3(ROWS/4), dim3(256), 0, stream,
                       K, QV, offs, elist, out);
}

// Round 10
// 107.129 us; speedup vs baseline: 4.8612x; 1.0444x over previous
//
#include <hip/hip_runtime.h>

#define BT 48
#define NN 2048
#define FF 64
#define EE 32768
#define ROWS (BT*NN)          // 98304

typedef __attribute__((ext_vector_type(2))) _Float16 half2v;
typedef __attribute__((ext_vector_type(8))) _Float16 half8v;
typedef __attribute__((ext_vector_type(4))) float float4v;

// pack two floats into fp16x2 bits (native casts -> v_cvt_f16_f32 + pack)
__device__ __forceinline__ unsigned cvt2h(float lo, float hi){
    union { half2v h; unsigned u; } c;
    c.h = half2v{(_Float16)lo, (_Float16)hi};
    return c.u;
}
__device__ __forceinline__ half2v h2(unsigned u){
    union { unsigned u; half2v h; } c; c.u = u; return c.h;
}

// ---------------- Kernel 1: fp16 MFMA projections (swapped operands) ----
// Block = 256 thr (4 waves), 64 x-rows. Wave w owns matrix w (0:K 1:Q 2:V
// 3:skip). Swapped MFMA: A = W tile, B = x tile -> D[feature][xrow], so
// each lane holds 4 CONSECUTIVE features -> fp16-pair packing is
// lane-local: no LDS exchange, no syncthreads.
// Kh row = 32 u32 (fp16 pairs); QV row = 64 u32 interleaved
// {q01,v01,q23,v23,...}; skip row = fp32 (float4 stores).
__global__ __launch_bounds__(256) void proj_kernel(
    const float* __restrict__ x,
    const float* __restrict__ Wk, const float* __restrict__ bk,
    const float* __restrict__ Wq, const float* __restrict__ bq,
    const float* __restrict__ Wv, const float* __restrict__ bv,
    const float* __restrict__ Ws, const float* __restrict__ bs,
    unsigned* __restrict__ Kh, unsigned* __restrict__ QV,
    float* __restrict__ out)
{
    const int tid = threadIdx.x;
    const int w  = tid >> 6;              // wave -> matrix
    const int l  = tid & 63;
    const int lr = l & 15;                // A-row (feature) / B-col (xrow)
    const int lh = l >> 4;                // k-group / D row-group
    const float* Wm = (w==0)?Wk:(w==1)?Wq:(w==2)?Wv:Ws;
    const float* bm = (w==0)?bk:(w==1)?bq:(w==2)?bv:bs;

    union FragH { unsigned u[4]; half8v h; };

    // A frags (W): af[ft][h].elem j' -> W[k0+j'][ft*16+lr], k0=h*32+lh*8
    FragH af[4][2];
    #pragma unroll
    for (int ft=0;ft<4;ft++)
        #pragma unroll
        for (int h=0;h<2;h++)
            #pragma unroll
            for (int jj=0;jj<4;jj++){
                const int k0 = h*32 + lh*8 + 2*jj;
                af[ft][h].u[jj] = cvt2h(Wm[(size_t)k0*FF + ft*16 + lr],
                                        Wm[(size_t)(k0+1)*FF + ft*16 + lr]);
            }

    // acc[ft][rt]: D rows = features ft*16+lh*4+j, D col = xrow rt*16+lr
    float4v acc[4][4];
    #pragma unroll
    for (int ft=0;ft<4;ft++){
        const float4 bv4 = *(const float4*)(bm + ft*16 + lh*4);
        #pragma unroll
        for (int rt=0;rt<4;rt++) acc[ft][rt] = float4v{bv4.x,bv4.y,bv4.z,bv4.w};
    }

    const int row0 = blockIdx.x * 64;
    #pragma unroll
    for (int rt=0;rt<4;rt++){
        const float* xr = x + (size_t)(row0 + rt*16 + lr)*FF + lh*8;
        const float4 xa0 = *(const float4*)(xr);
        const float4 xa1 = *(const float4*)(xr + 4);
        const float4 xb0 = *(const float4*)(xr + 32);
        const float4 xb1 = *(const float4*)(xr + 36);
        FragH b0, b1;
        b0.u[0]=cvt2h(xa0.x,xa0.y); b0.u[1]=cvt2h(xa0.z,xa0.w);
        b0.u[2]=cvt2h(xa1.x,xa1.y); b0.u[3]=cvt2h(xa1.z,xa1.w);
        b1.u[0]=cvt2h(xb0.x,xb0.y); b1.u[1]=cvt2h(xb0.z,xb0.w);
        b1.u[2]=cvt2h(xb1.x,xb1.y); b1.u[3]=cvt2h(xb1.z,xb1.w);
        #pragma unroll
        for (int ft=0;ft<4;ft++){
            acc[ft][rt] = __builtin_amdgcn_mfma_f32_16x16x32_f16(af[ft][0].h, b0.h, acc[ft][rt], 0,0,0);
            acc[ft][rt] = __builtin_amdgcn_mfma_f32_16x16x32_f16(af[ft][1].h, b1.h, acc[ft][rt], 0,0,0);
        }
    }

    // stores: row = x-row; features ft*16+lh*4+{0..3} -> pairs p0=ft*8+lh*2, p0+1
    #pragma unroll
    for (int ft=0;ft<4;ft++){
        const int p0 = ft*8 + lh*2;
        #pragma unroll
        for (int rt=0;rt<4;rt++){
            const size_t row = (size_t)(row0 + rt*16 + lr);
            const float4v a = acc[ft][rt];
            if (w == 0){
                uint2 st; st.x = cvt2h(a[0],a[1]); st.y = cvt2h(a[2],a[3]);
                *(uint2*)(Kh + row*32 + p0) = st;
            } else if (w == 1){           // q pairs at even u32 slots
                QV[row*FF + 2*p0]     = cvt2h(a[0],a[1]);
                QV[row*FF + 2*(p0+1)] = cvt2h(a[2],a[3]);
            } else if (w == 2){           // v pairs at odd u32 slots
                QV[row*FF + 2*p0 + 1]     = cvt2h(a[0],a[1]);
                QV[row*FF + 2*(p0+1) + 1] = cvt2h(a[2],a[3]);
            } else {
                *(float4*)(out + row*FF + ft*16 + lh*4) = make_float4(a[0],a[1],a[2],a[3]);
            }
        }
    }
}

// ---------------- Kernel 2: fused CSR build (64 blocks, spin barriers) ----
// bar[0..2] + flag zeroed by hipMemsetAsync before this kernel each launch.
// 64 blocks << 256 CUs -> co-resident; linear-chain graph.
__device__ __forceinline__ void gbar(int* ctr, int nblk){
    __syncthreads();
    if (threadIdx.x == 0){
        __threadfence();
        atomicAdd(ctr, 1);
        while (__hip_atomic_load(ctr, __ATOMIC_ACQUIRE, __HIP_MEMORY_SCOPE_AGENT) < nblk) {}
    }
    __syncthreads();
}

__global__ __launch_bounds__(256) void csr_kernel(
    const unsigned int* __restrict__ ew,
    int* __restrict__ flag, int* __restrict__ bar,
    int* __restrict__ deg, int* __restrict__ offs,
    int* __restrict__ cur, int* __restrict__ elist)
{
    const int t = threadIdx.x, b = blockIdx.x;
    const int gtid = b*256 + t;           // 16384 threads

    for (int i=gtid; i<NN; i+=16384) deg[i] = 0;
    if (gtid < 16) elist[EE + gtid] = 0;  // pad (masked in agg tail)
    unsigned f = 0;
    for (int i=gtid; i<8192; i+=16384) f |= ew[2*i+1];
    if (f) atomicOr((unsigned int*)flag, f);
    gbar(bar+0, 64);
    const bool i64 = (*flag == 0);

    for (int e=gtid; e<EE; e+=16384){
        const int d = i64 ? (int)ew[2*(EE+e)] : (int)ew[EE+e];
        atomicAdd(&deg[d], 1);
    }
    gbar(bar+1, 64);

    if (b == 0){
        __shared__ int wsums[4];
        const int base = t*8;
        int v[8], pre[8];
        #pragma unroll
        for (int j=0;j<8;j++) v[j] = deg[base+j];
        pre[0] = 0;
        #pragma unroll
        for (int j=1;j<8;j++) pre[j] = pre[j-1] + v[j-1];
        const int s = pre[7] + v[7];
        int inc = s;
        const int lane = t & 63, wid = t >> 6;
        #pragma unroll
        for (int d=1; d<64; d<<=1){ int tt = __shfl_up(inc, d, 64); if (lane>=d) inc += tt; }
        if (lane == 63) wsums[wid] = inc;
        __syncthreads();
        if (t == 0){ int a=0; for (int k2=0;k2<4;k2++){ int tt=wsums[k2]; wsums[k2]=a; a+=tt; } }
        __syncthreads();
        const int excl = wsums[wid] + (inc - s);
        #pragma unroll
        for (int j=0;j<8;j++){ offs[base+j] = excl + pre[j]; cur[base+j] = excl + pre[j]; }
        if (t == 255) offs[NN] = excl + s;
    }
    gbar(bar+2, 64);

    for (int e=gtid; e<EE; e+=16384){
        int d, s;
        if (i64){ d = (int)ew[2*(EE+e)]; s = (int)ew[2*e]; }
        else    { d = (int)ew[EE+e];     s = (int)ew[e];   }
        const int pos = atomicAdd(&cur[d], 1);
        elist[pos] = s;
    }
}

// ---------------- Kernel 3: gather + gate + aggregate (packed fp16) ----
// wave = (bt,node); sub = edge slot, fq = feature quad. Per edge: ONE
// uint4 gather {q01,v01,q23,v23} + ~8 v_pk ops (add, mul, max, fma x2).
// Native _Float16 vector ops -> v_pk_add/mul/max/fma_f16.
// XCD-pinned bt groups (block b -> XCD b%8).
#define HEDGE(U) { \
    half2v g01 = k01 + h2((U).x); \
    g01 = __builtin_elementwise_max(g01, g01*c001); \
    acc01 += g01 * h2((U).y); \
    half2v g23 = k23 + h2((U).z); \
    g23 = __builtin_elementwise_max(g23, g23*c001); \
    acc23 += g23 * h2((U).w); }
#define HEDGEM(U, M) { \
    half2v g01 = k01 + h2((U).x); \
    g01 = __builtin_elementwise_max(g01, g01*c001); \
    acc01 += g01 * (h2((U).y) * (M)); \
    half2v g23 = k23 + h2((U).z); \
    g23 = __builtin_elementwise_max(g23, g23*c001); \
    acc23 += g23 * (h2((U).w) * (M)); }

__global__ __launch_bounds__(256) void agg_kernel(
    const unsigned* __restrict__ Kh, const unsigned* __restrict__ QV,
    const int* __restrict__ offs, const int* __restrict__ elist,
    float* __restrict__ out)
{
    const int tid  = threadIdx.x;
    const int lane = tid & 63;
    const int w    = tid >> 6;
    const int b    = blockIdx.x;          // 24576 blocks
    const int xcd  = b & 7;
    const int li   = b >> 3;
    const int bt   = xcd*6 + (li >> 9);   // 6 bts per XCD
    const int node = ((li & 511) << 2) | w;
    const int sub  = lane >> 4;
    const int fq   = lane & 15;
    const size_t S = (size_t)NN*FF;

    const uint2 ku = *(const uint2*)(Kh + ((size_t)bt*NN + node)*32 + 2*fq);
    const half2v k01 = h2(ku.x), k23 = h2(ku.y);
    const half2v c001 = half2v{(_Float16)0.01f, (_Float16)0.01f};
    const half2v one2 = half2v{(_Float16)1.f, (_Float16)1.f};
    const half2v zero2 = half2v{(_Float16)0.f, (_Float16)0.f};
    const unsigned* QVb = QV + (size_t)bt*S;

    half2v acc01 = zero2, acc23 = zero2;
    const int s0 = offs[node], s1 = offs[node+1];

    for (int i = s0; i < s1; i += 16){
        const int rem  = s1 - i;          // wave-uniform
        const int base = i + 4*sub;
        const int e0 = elist[base+0];
        const int e1 = elist[base+1];
        const int e2 = elist[base+2];
        const int e3 = elist[base+3];
        const uint4 u0 = *(const uint4*)(QVb + (((unsigned)e0)<<6) + (fq<<2));
        const uint4 u1 = *(const uint4*)(QVb + (((unsigned)e1)<<6) + (fq<<2));
        const uint4 u2 = *(const uint4*)(QVb + (((unsigned)e2)<<6) + (fq<<2));
        const uint4 u3 = *(const uint4*)(QVb + (((unsigned)e3)<<6) + (fq<<2));
        if (rem >= 16){
            HEDGE(u0); HEDGE(u1); HEDGE(u2); HEDGE(u3);
        } else {
            const half2v m0 = (4*sub+0 < rem) ? one2 : zero2;
            const half2v m1 = (4*sub+1 < rem) ? one2 : zero2;
            const half2v m2 = (4*sub+2 < rem) ? one2 : zero2;
            const half2v m3 = (4*sub+3 < rem) ? one2 : zero2;
            HEDGEM(u0, m0); HEDGEM(u1, m1); HEDGEM(u2, m2); HEDGEM(u3, m3);
        }
    }

    float4 acc = make_float4((float)acc01[0], (float)acc01[1],
                             (float)acc23[0], (float)acc23[1]);

    acc.x += __shfl_xor(acc.x, 16, 64); acc.y += __shfl_xor(acc.y, 16, 64);
    acc.z += __shfl_xor(acc.z, 16, 64); acc.w += __shfl_xor(acc.w, 16, 64);
    acc.x += __shfl_xor(acc.x, 32, 64); acc.y += __shfl_xor(acc.y, 32, 64);
    acc.z += __shfl_xor(acc.z, 32, 64); acc.w += __shfl_xor(acc.w, 32, 64);

    if (sub == 0){
        const size_t rowb = ((size_t)bt*NN + node)*FF;
        const float4 sk = *(const float4*)(out + rowb + fq*4);  // skip+bias
        float4 r;
        r.x = acc.x + sk.x; r.y = acc.y + sk.y;
        r.z = acc.z + sk.z; r.w = acc.w + sk.w;
        *(float4*)(out + rowb + fq*4) = r;
    }
}

extern "C" void kernel_launch(void* const* d_in, const int* in_sizes, int n_in,
                              void* d_out, int out_size, void* d_ws, size_t ws_size,
                              hipStream_t stream)
{
    const float* x  = (const float*)d_in[0];
    const unsigned int* ew = (const unsigned int*)d_in[1];
    const float* Wk = (const float*)d_in[2];
    const float* bk = (const float*)d_in[3];
    const float* Wq = (const float*)d_in[4];
    const float* bq = (const float*)d_in[5];
    const float* Wv = (const float*)d_in[6];
    const float* bv = (const float*)d_in[7];
    const float* Ws = (const float*)d_in[8];
    const float* bs = (const float*)d_in[9];
    float* out = (float*)d_out;

    const size_t n = (size_t)ROWS*FF;
    unsigned* Kh = (unsigned*)d_ws;       // ROWS*32 u32
    unsigned* QV = Kh + (size_t)ROWS*32;  // ROWS*64 u32
    int* meta  = (int*)(QV + n);
    int* flag  = meta;
    int* bar   = meta + 4;
    int* deg   = meta + 16;
    int* offs  = deg + NN;
    int* cur   = offs + NN + 16;
    int* elist = cur + NN;

    hipMemsetAsync(meta, 0, 32, stream);

    hipLaunchKernelGGL(proj_kernel, dim3(ROWS/64), dim3(256), 0, stream,
                       x, Wk,bk, Wq,bq, Wv,bv, Ws,bs, Kh, QV, out);
    hipLaunchKernelGGL(csr_kernel, dim3(64), dim3(256), 0, stream,
                       ew, flag, bar, deg, offs, cur, elist);
    hipLaunchKernelGGL(agg_kernel, dim3(ROWS/4), dim3(256), 0, stream,
                       Kh, QV, offs, elist, out);
}

// Round 11
// 103.521 us; speedup vs baseline: 5.0306x; 1.0348x over previous
//
#include <hip/hip_runtime.h>

#define BT 48
#define NN 2048
#define FF 64
#define EE 32768
#define ROWS (BT*NN)          // 98304
#define PRB 256               // rows per proj block -> 384 blocks

typedef __attribute__((ext_vector_type(2))) _Float16 half2v;
typedef __attribute__((ext_vector_type(8))) _Float16 half8v;
typedef __attribute__((ext_vector_type(4))) float float4v;

__device__ __forceinline__ unsigned cvt2h(float lo, float hi){
    union { half2v h; unsigned u; } c;
    c.h = half2v{(_Float16)lo, (_Float16)hi};
    return c.u;
}
__device__ __forceinline__ half2v h2(unsigned u){
    union { unsigned u; half2v h; } c; c.u = u; return c.h;
}

// ---------------- Kernel 1: fp16 MFMA projections (swapped operands) ----
// Block = 256 thr (4 waves), 256 x-rows (W-fragment preamble amortized 4x
// vs R10's 64-row blocks; rt-loop keeps a deep VMEM/MFMA pipeline and acc
// lives only per-iteration). Wave w owns matrix w (0:K 1:Q 2:V 3:skip).
// Swapped MFMA: A = W tile, B = x tile -> D[feature][xrow]; each lane holds
// 4 consecutive features -> fp16-pair packing is lane-local (no LDS).
// Block 0 also zeroes meta[0..7] for csr (replaces the memset dispatch).
__global__ __launch_bounds__(256) void proj_kernel(
    const float* __restrict__ x,
    const float* __restrict__ Wk, const float* __restrict__ bk,
    const float* __restrict__ Wq, const float* __restrict__ bq,
    const float* __restrict__ Wv, const float* __restrict__ bv,
    const float* __restrict__ Ws, const float* __restrict__ bs,
    unsigned* __restrict__ Kh, unsigned* __restrict__ QV,
    float* __restrict__ out, int* __restrict__ meta)
{
    if (blockIdx.x == 0 && threadIdx.x < 8) meta[threadIdx.x] = 0;

    const int tid = threadIdx.x;
    const int w  = tid >> 6;              // wave -> matrix
    const int l  = tid & 63;
    const int lr = l & 15;                // A-row (feature) / B-col (xrow)
    const int lh = l >> 4;                // k-group / D row-group
    const float* Wm = (w==0)?Wk:(w==1)?Wq:(w==2)?Wv:Ws;
    const float* bm = (w==0)?bk:(w==1)?bq:(w==2)?bv:bs;

    union FragH { unsigned u[4]; half8v h; };

    // A frags (W): af[ft][h].elem j' -> W[k0+j'][ft*16+lr], k0=h*32+lh*8
    FragH af[4][2];
    #pragma unroll
    for (int ft=0;ft<4;ft++)
        #pragma unroll
        for (int h=0;h<2;h++)
            #pragma unroll
            for (int jj=0;jj<4;jj++){
                const int k0 = h*32 + lh*8 + 2*jj;
                af[ft][h].u[jj] = cvt2h(Wm[(size_t)k0*FF + ft*16 + lr],
                                        Wm[(size_t)(k0+1)*FF + ft*16 + lr]);
            }

    float4 bias4[4];
    #pragma unroll
    for (int ft=0;ft<4;ft++) bias4[ft] = *(const float4*)(bm + ft*16 + lh*4);

    const int row0 = blockIdx.x * PRB;
    #pragma unroll 4
    for (int rt=0; rt<PRB/16; ++rt){
        const float* xr = x + (size_t)(row0 + rt*16 + lr)*FF + lh*8;
        const float4 xa0 = *(const float4*)(xr);
        const float4 xa1 = *(const float4*)(xr + 4);
        const float4 xb0 = *(const float4*)(xr + 32);
        const float4 xb1 = *(const float4*)(xr + 36);
        FragH b0, b1;
        b0.u[0]=cvt2h(xa0.x,xa0.y); b0.u[1]=cvt2h(xa0.z,xa0.w);
        b0.u[2]=cvt2h(xa1.x,xa1.y); b0.u[3]=cvt2h(xa1.z,xa1.w);
        b1.u[0]=cvt2h(xb0.x,xb0.y); b1.u[1]=cvt2h(xb0.z,xb0.w);
        b1.u[2]=cvt2h(xb1.x,xb1.y); b1.u[3]=cvt2h(xb1.z,xb1.w);

        const size_t row = (size_t)(row0 + rt*16 + lr);
        #pragma unroll
        for (int ft=0;ft<4;ft++){
            float4v acc = float4v{bias4[ft].x, bias4[ft].y, bias4[ft].z, bias4[ft].w};
            acc = __builtin_amdgcn_mfma_f32_16x16x32_f16(af[ft][0].h, b0.h, acc, 0,0,0);
            acc = __builtin_amdgcn_mfma_f32_16x16x32_f16(af[ft][1].h, b1.h, acc, 0,0,0);
            const int p0 = ft*8 + lh*2;
            if (w == 0){
                uint2 st; st.x = cvt2h(acc[0],acc[1]); st.y = cvt2h(acc[2],acc[3]);
                *(uint2*)(Kh + row*32 + p0) = st;
            } else if (w == 1){           // q pairs at even u32 slots
                QV[row*FF + 2*p0]     = cvt2h(acc[0],acc[1]);
                QV[row*FF + 2*(p0+1)] = cvt2h(acc[2],acc[3]);
            } else if (w == 2){           // v pairs at odd u32 slots
                QV[row*FF + 2*p0 + 1]     = cvt2h(acc[0],acc[1]);
                QV[row*FF + 2*(p0+1) + 1] = cvt2h(acc[2],acc[3]);
            } else {
                *(float4*)(out + row*FF + ft*16 + lh*4) =
                    make_float4(acc[0],acc[1],acc[2],acc[3]);
            }
        }
    }
}

// ---------------- Kernel 2: fused CSR build (64 blocks, spin barriers) ----
// meta (flag+bar) zeroed by proj_kernel block 0 each launch (stream order
// guarantees visibility). 64 blocks << 256 CUs -> co-resident.
__device__ __forceinline__ void gbar(int* ctr, int nblk){
    __syncthreads();
    if (threadIdx.x == 0){
        __threadfence();
        atomicAdd(ctr, 1);
        while (__hip_atomic_load(ctr, __ATOMIC_ACQUIRE, __HIP_MEMORY_SCOPE_AGENT) < nblk) {}
    }
    __syncthreads();
}

__global__ __launch_bounds__(256) void csr_kernel(
    const unsigned int* __restrict__ ew,
    int* __restrict__ flag, int* __restrict__ bar,
    int* __restrict__ deg, int* __restrict__ offs,
    int* __restrict__ cur, int* __restrict__ elist)
{
    const int t = threadIdx.x, b = blockIdx.x;
    const int gtid = b*256 + t;           // 16384 threads

    for (int i=gtid; i<NN; i+=16384) deg[i] = 0;
    if (gtid < 16) elist[EE + gtid] = 0;  // pad (masked in agg tail)
    unsigned f = 0;
    for (int i=gtid; i<8192; i+=16384) f |= ew[2*i+1];
    if (f) atomicOr((unsigned int*)flag, f);
    gbar(bar+0, 64);
    const bool i64 = (*flag == 0);

    for (int e=gtid; e<EE; e+=16384){
        const int d = i64 ? (int)ew[2*(EE+e)] : (int)ew[EE+e];
        atomicAdd(&deg[d], 1);
    }
    gbar(bar+1, 64);

    if (b == 0){
        __shared__ int wsums[4];
        const int base = t*8;
        int v[8], pre[8];
        #pragma unroll
        for (int j=0;j<8;j++) v[j] = deg[base+j];
        pre[0] = 0;
        #pragma unroll
        for (int j=1;j<8;j++) pre[j] = pre[j-1] + v[j-1];
        const int s = pre[7] + v[7];
        int inc = s;
        const int lane = t & 63, wid = t >> 6;
        #pragma unroll
        for (int d=1; d<64; d<<=1){ int tt = __shfl_up(inc, d, 64); if (lane>=d) inc += tt; }
        if (lane == 63) wsums[wid] = inc;
        __syncthreads();
        if (t == 0){ int a=0; for (int k2=0;k2<4;k2++){ int tt=wsums[k2]; wsums[k2]=a; a+=tt; } }
        __syncthreads();
        const int excl = wsums[wid] + (inc - s);
        #pragma unroll
        for (int j=0;j<8;j++){ offs[base+j] = excl + pre[j]; cur[base+j] = excl + pre[j]; }
        if (t == 255) offs[NN] = excl + s;
    }
    gbar(bar+2, 64);

    for (int e=gtid; e<EE; e+=16384){
        int d, s;
        if (i64){ d = (int)ew[2*(EE+e)]; s = (int)ew[2*e]; }
        else    { d = (int)ew[EE+e];     s = (int)ew[e];   }
        const int pos = atomicAdd(&cur[d], 1);
        elist[pos] = s;
    }
}

// ---------------- Kernel 3: gather + gate + aggregate (packed fp16) ----
// wave = (bt,node); sub = edge slot, fq = feature quad. Per edge: ONE
// uint4 gather {q01,v01,q23,v23} + 8 v_pk ops. int4 elist load (16B
// aligned). XCD-pinned bt groups (block b -> XCD b%8).
#define HEDGE(U) { \
    half2v g01 = k01 + h2((U).x); \
    g01 = __builtin_elementwise_max(g01, g01*c001); \
    acc01 += g01 * h2((U).y); \
    half2v g23 = k23 + h2((U).z); \
    g23 = __builtin_elementwise_max(g23, g23*c001); \
    acc23 += g23 * h2((U).w); }
#define HEDGEM(U, M) { \
    half2v g01 = k01 + h2((U).x); \
    g01 = __builtin_elementwise_max(g01, g01*c001); \
    acc01 += g01 * (h2((U).y) * (M)); \
    half2v g23 = k23 + h2((U).z); \
    g23 = __builtin_elementwise_max(g23, g23*c001); \
    acc23 += g23 * (h2((U).w) * (M)); }

__global__ __launch_bounds__(256) void agg_kernel(
    const unsigned* __restrict__ Kh, const unsigned* __restrict__ QV,
    const int* __restrict__ offs, const int* __restrict__ elist,
    float* __restrict__ out)
{
    const int tid  = threadIdx.x;
    const int lane = tid & 63;
    const int w    = tid >> 6;
    const int b    = blockIdx.x;          // 24576 blocks
    const int xcd  = b & 7;
    const int li   = b >> 3;
    const int bt   = xcd*6 + (li >> 9);   // 6 bts per XCD
    const int node = ((li & 511) << 2) | w;
    const int sub  = lane >> 4;
    const int fq   = lane & 15;
    const size_t S = (size_t)NN*FF;

    const uint2 ku = *(const uint2*)(Kh + ((size_t)bt*NN + node)*32 + 2*fq);
    const half2v k01 = h2(ku.x), k23 = h2(ku.y);
    const half2v c001 = half2v{(_Float16)0.01f, (_Float16)0.01f};
    const half2v one2 = half2v{(_Float16)1.f, (_Float16)1.f};
    const half2v zero2 = half2v{(_Float16)0.f, (_Float16)0.f};
    const unsigned* QVb = QV + (size_t)bt*S;

    half2v acc01 = zero2, acc23 = zero2;
    const int s0 = offs[node], s1 = offs[node+1];

    for (int i = s0; i < s1; i += 16){
        const int rem  = s1 - i;          // wave-uniform
        const int4 ev = *(const int4*)(elist + i + 4*sub);
        const uint4 u0 = *(const uint4*)(QVb + (((unsigned)ev.x)<<6) + (fq<<2));
        const uint4 u1 = *(const uint4*)(QVb + (((unsigned)ev.y)<<6) + (fq<<2));
        const uint4 u2 = *(const uint4*)(QVb + (((unsigned)ev.z)<<6) + (fq<<2));
        const uint4 u3 = *(const uint4*)(QVb + (((unsigned)ev.w)<<6) + (fq<<2));
        if (rem >= 16){
            HEDGE(u0); HEDGE(u1); HEDGE(u2); HEDGE(u3);
        } else {
            const half2v m0 = (4*sub+0 < rem) ? one2 : zero2;
            const half2v m1 = (4*sub+1 < rem) ? one2 : zero2;
            const half2v m2 = (4*sub+2 < rem) ? one2 : zero2;
            const half2v m3 = (4*sub+3 < rem) ? one2 : zero2;
            HEDGEM(u0, m0); HEDGEM(u1, m1); HEDGEM(u2, m2); HEDGEM(u3, m3);
        }
    }

    float4 acc = make_float4((float)acc01[0], (float)acc01[1],
                             (float)acc23[0], (float)acc23[1]);

    acc.x += __shfl_xor(acc.x, 16, 64); acc.y += __shfl_xor(acc.y, 16, 64);
    acc.z += __shfl_xor(acc.z, 16, 64); acc.w += __shfl_xor(acc.w, 16, 64);
    acc.x += __shfl_xor(acc.x, 32, 64); acc.y += __shfl_xor(acc.y, 32, 64);
    acc.z += __shfl_xor(acc.z, 32, 64); acc.w += __shfl_xor(acc.w, 32, 64);

    if (sub == 0){
        const size_t rowb = ((size_t)bt*NN + node)*FF;
        const float4 sk = *(const float4*)(out + rowb + fq*4);  // skip+bias
        float4 r;
        r.x = acc.x + sk.x; r.y = acc.y + sk.y;
        r.z = acc.z + sk.z; r.w = acc.w + sk.w;
        *(float4*)(out + rowb + fq*4) = r;
    }
}

extern "C" void kernel_launch(void* const* d_in, const int* in_sizes, int n_in,
                              void* d_out, int out_size, void* d_ws, size_t ws_size,
                              hipStream_t stream)
{
    const float* x  = (const float*)d_in[0];
    const unsigned int* ew = (const unsigned int*)d_in[1];
    const float* Wk = (const float*)d_in[2];
    const float* bk = (const float*)d_in[3];
    const float* Wq = (const float*)d_in[4];
    const float* bq = (const float*)d_in[5];
    const float* Wv = (const float*)d_in[6];
    const float* bv = (const float*)d_in[7];
    const float* Ws = (const float*)d_in[8];
    const float* bs = (const float*)d_in[9];
    float* out = (float*)d_out;

    const size_t n = (size_t)ROWS*FF;
    unsigned* Kh = (unsigned*)d_ws;       // ROWS*32 u32
    unsigned* QV = Kh + (size_t)ROWS*32;  // ROWS*64 u32
    int* meta  = (int*)(QV + n);
    int* flag  = meta;
    int* bar   = meta + 4;
    int* deg   = meta + 16;
    int* offs  = deg + NN;
    int* cur   = offs + NN + 16;
    int* elist = cur + NN;

    hipLaunchKernelGGL(proj_kernel, dim3(ROWS/PRB), dim3(256), 0, stream,
                       x, Wk,bk, Wq,bq, Wv,bv, Ws,bs, Kh, QV, out, meta);
    hipLaunchKernelGGL(csr_kernel, dim3(64), dim3(256), 0, stream,
                       ew, flag, bar, deg, offs, cur, elist);
    hipLaunchKernelGGL(agg_kernel, dim3(ROWS/4), dim3(256), 0, stream,
                       Kh, QV, offs, elist, out);
}

// Round 12
// 95.562 us; speedup vs baseline: 5.4496x; 1.0833x over previous
//
#include <hip/hip_runtime.h>

#define BT 48
#define NN 2048
#define FF 64
#define EE 32768
#define ROWS (BT*NN)          // 98304

typedef __attribute__((ext_vector_type(2))) _Float16 half2v;
typedef __attribute__((ext_vector_type(8))) _Float16 half8v;
typedef __attribute__((ext_vector_type(4))) float float4v;

__device__ __forceinline__ unsigned cvt2h(float lo, float hi){
    union { half2v h; unsigned u; } c;
    c.h = half2v{(_Float16)lo, (_Float16)hi};
    return c.u;
}
__device__ __forceinline__ half2v h2(unsigned u){
    union { unsigned u; half2v h; } c; c.u = u; return c.h;
}

union FragH { unsigned u[4]; half8v h; uint4 u4; };

// ---------------- Kernel 0: W fragment pre-pack (+ meta zero) ----------
// Wp[((mat*4+ft)*2+h)*256 + l*4 + jj] = fp16-pair of W[k0..k0+1][c],
// k0 = h*32+(l>>4)*8+2jj, c = ft*16+(l&15). proj then loads frags as
// coalesced dwordx4 (lane l -> offset l*4) instead of 64 scalar loads.
__global__ __launch_bounds__(256) void wpack_kernel(
    const float* __restrict__ Wk, const float* __restrict__ Wq,
    const float* __restrict__ Wv, const float* __restrict__ Ws,
    unsigned* __restrict__ Wp, int* __restrict__ meta)
{
    const int t = threadIdx.x;
    if (t < 8) meta[t] = 0;
    for (int idx = t; idx < 8192; idx += 256){
        const int mat = idx >> 11;
        const int r   = idx & 2047;
        const int ft  = r >> 9;
        const int h   = (r >> 8) & 1;
        const int l   = (r >> 2) & 63;
        const int jj  = r & 3;
        const float* W = (mat==0)?Wk:(mat==1)?Wq:(mat==2)?Wv:Ws;
        const int k0 = h*32 + (l>>4)*8 + 2*jj;
        const int c  = ft*16 + (l&15);
        Wp[idx] = cvt2h(W[(size_t)k0*FF + c], W[(size_t)(k0+1)*FF + c]);
    }
}

// ---------------- Kernel 1: fp16 MFMA projections, 2 mats/wave ----------
// 768 blocks x 4 waves; waves {0,1} rows [row0,row0+64), {2,3} next 64.
// wm = w&1: wm==0 -> (K, skip); wm==1 -> (Q, V). Q+V in ONE wave => QV
// store is a single dwordx4 {q01,v01,q23,v23}; x-loads duplicated only 2x.
// Swapped MFMA (A=W, B=x): D[feature][xrow], lane holds 4 consecutive
// features (f0 = ft*16+lh*4), lane-local fp16 packing.
__global__ __launch_bounds__(256) void proj_kernel(
    const float* __restrict__ x, const unsigned* __restrict__ Wp,
    const float* __restrict__ bk, const float* __restrict__ bq,
    const float* __restrict__ bv, const float* __restrict__ bs,
    unsigned* __restrict__ Kh, unsigned* __restrict__ QV,
    float* __restrict__ out)
{
    const int tid = threadIdx.x;
    const int w  = tid >> 6;
    const int l  = tid & 63;
    const int lr = l & 15;
    const int lh = l >> 4;
    const int wm = w & 1;                 // 0: K+skip, 1: Q+V
    const int matA = wm ? 1 : 0;          // Q : K
    const int matB = wm ? 2 : 3;          // V : skip
    const float* bmA = wm ? bq : bk;
    const float* bmB = wm ? bv : bs;

    FragH afA[4][2], afB[4][2];
    #pragma unroll
    for (int ft=0;ft<4;ft++)
        #pragma unroll
        for (int h=0;h<2;h++){
            afA[ft][h].u4 = *(const uint4*)(Wp + ((matA*4+ft)*2+h)*256 + l*4);
            afB[ft][h].u4 = *(const uint4*)(Wp + ((matB*4+ft)*2+h)*256 + l*4);
        }
    float4 biasA[4], biasB[4];
    #pragma unroll
    for (int ft=0;ft<4;ft++){
        biasA[ft] = *(const float4*)(bmA + ft*16 + lh*4);
        biasB[ft] = *(const float4*)(bmB + ft*16 + lh*4);
    }

    const int row0 = blockIdx.x * 128 + (w>>1)*64;
    #pragma unroll 2
    for (int rt=0; rt<4; ++rt){
        const int r16 = row0 + rt*16;
        const float* xr = x + (size_t)(r16 + lr)*FF + lh*8;
        const float4 xa0 = *(const float4*)(xr);
        const float4 xa1 = *(const float4*)(xr + 4);
        const float4 xb0 = *(const float4*)(xr + 32);
        const float4 xb1 = *(const float4*)(xr + 36);
        FragH b0, b1;
        b0.u[0]=cvt2h(xa0.x,xa0.y); b0.u[1]=cvt2h(xa0.z,xa0.w);
        b0.u[2]=cvt2h(xa1.x,xa1.y); b0.u[3]=cvt2h(xa1.z,xa1.w);
        b1.u[0]=cvt2h(xb0.x,xb0.y); b1.u[1]=cvt2h(xb0.z,xb0.w);
        b1.u[2]=cvt2h(xb1.x,xb1.y); b1.u[3]=cvt2h(xb1.z,xb1.w);

        const size_t row = (size_t)(r16 + lr);
        #pragma unroll
        for (int ft=0;ft<4;ft++){
            float4v aA = float4v{biasA[ft].x, biasA[ft].y, biasA[ft].z, biasA[ft].w};
            aA = __builtin_amdgcn_mfma_f32_16x16x32_f16(afA[ft][0].h, b0.h, aA, 0,0,0);
            aA = __builtin_amdgcn_mfma_f32_16x16x32_f16(afA[ft][1].h, b1.h, aA, 0,0,0);
            float4v aB = float4v{biasB[ft].x, biasB[ft].y, biasB[ft].z, biasB[ft].w};
            aB = __builtin_amdgcn_mfma_f32_16x16x32_f16(afB[ft][0].h, b0.h, aB, 0,0,0);
            aB = __builtin_amdgcn_mfma_f32_16x16x32_f16(afB[ft][1].h, b1.h, aB, 0,0,0);
            if (wm == 0){
                uint2 st; st.x = cvt2h(aA[0],aA[1]); st.y = cvt2h(aA[2],aA[3]);
                *(uint2*)(Kh + row*32 + ft*8 + lh*2) = st;
                *(float4*)(out + row*FF + ft*16 + lh*4) =
                    make_float4(aB[0],aB[1],aB[2],aB[3]);
            } else {
                uint4 st;
                st.x = cvt2h(aA[0],aA[1]); st.y = cvt2h(aB[0],aB[1]);
                st.z = cvt2h(aA[2],aA[3]); st.w = cvt2h(aB[2],aB[3]);
                *(uint4*)(QV + row*FF + ft*16 + lh*4) = st;
            }
        }
    }
}

// ---------------- Kernel 2: fused CSR build (64 blocks, spin barriers) ----
__device__ __forceinline__ void gbar(int* ctr, int nblk){
    __syncthreads();
    if (threadIdx.x == 0){
        __threadfence();
        atomicAdd(ctr, 1);
        while (__hip_atomic_load(ctr, __ATOMIC_ACQUIRE, __HIP_MEMORY_SCOPE_AGENT) < nblk) {}
    }
    __syncthreads();
}

__global__ __launch_bounds__(256) void csr_kernel(
    const unsigned int* __restrict__ ew,
    int* __restrict__ flag, int* __restrict__ bar,
    int* __restrict__ deg, int* __restrict__ offs,
    int* __restrict__ cur, int* __restrict__ elist)
{
    const int t = threadIdx.x, b = blockIdx.x;
    const int gtid = b*256 + t;           // 16384 threads

    for (int i=gtid; i<NN; i+=16384) deg[i] = 0;
    if (gtid < 16) elist[EE + gtid] = 0;  // pad (masked in agg tail)
    unsigned f = 0;
    for (int i=gtid; i<8192; i+=16384) f |= ew[2*i+1];
    if (f) atomicOr((unsigned int*)flag, f);
    gbar(bar+0, 64);
    const bool i64 = (*flag == 0);

    for (int e=gtid; e<EE; e+=16384){
        const int d = i64 ? (int)ew[2*(EE+e)] : (int)ew[EE+e];
        atomicAdd(&deg[d], 1);
    }
    gbar(bar+1, 64);

    if (b == 0){
        __shared__ int wsums[4];
        const int base = t*8;
        int v[8], pre[8];
        #pragma unroll
        for (int j=0;j<8;j++) v[j] = deg[base+j];
        pre[0] = 0;
        #pragma unroll
        for (int j=1;j<8;j++) pre[j] = pre[j-1] + v[j-1];
        const int s = pre[7] + v[7];
        int inc = s;
        const int lane = t & 63, wid = t >> 6;
        #pragma unroll
        for (int d=1; d<64; d<<=1){ int tt = __shfl_up(inc, d, 64); if (lane>=d) inc += tt; }
        if (lane == 63) wsums[wid] = inc;
        __syncthreads();
        if (t == 0){ int a=0; for (int k2=0;k2<4;k2++){ int tt=wsums[k2]; wsums[k2]=a; a+=tt; } }
        __syncthreads();
        const int excl = wsums[wid] + (inc - s);
        #pragma unroll
        for (int j=0;j<8;j++){ offs[base+j] = excl + pre[j]; cur[base+j] = excl + pre[j]; }
        if (t == 255) offs[NN] = excl + s;
    }
    gbar(bar+2, 64);

    for (int e=gtid; e<EE; e+=16384){
        int d, s;
        if (i64){ d = (int)ew[2*(EE+e)]; s = (int)ew[2*e]; }
        else    { d = (int)ew[EE+e];     s = (int)ew[e];   }
        const int pos = atomicAdd(&cur[d], 1);
        elist[pos] = s;
    }
}

// ---------------- Kernel 3: gather + gate + aggregate (fp16, 2 bt/wave) --
// wave = (btpair, node): bt0=2p, bt1=2p+1 share elist/offs/addressing ->
// per-wave prologue/epilogue amortized 2x. Per edge: TWO uint4 gathers
// (one per bt) + 16 v_pk ops. XCD-pinned: 3 bt-pairs per XCD (1MB QV in L2).
#define HEDGE2(U, KA, KB, A01, A23) { \
    half2v g01 = (KA) + h2((U).x); \
    g01 = __builtin_elementwise_max(g01, g01*c001); \
    (A01) += g01 * h2((U).y); \
    half2v g23 = (KB) + h2((U).z); \
    g23 = __builtin_elementwise_max(g23, g23*c001); \
    (A23) += g23 * h2((U).w); }
#define HEDGE2M(U, KA, KB, A01, A23, M) { \
    half2v g01 = (KA) + h2((U).x); \
    g01 = __builtin_elementwise_max(g01, g01*c001); \
    (A01) += g01 * (h2((U).y) * (M)); \
    half2v g23 = (KB) + h2((U).z); \
    g23 = __builtin_elementwise_max(g23, g23*c001); \
    (A23) += g23 * (h2((U).w) * (M)); }

__global__ __launch_bounds__(256) void agg_kernel(
    const unsigned* __restrict__ Kh, const unsigned* __restrict__ QV,
    const int* __restrict__ offs, const int* __restrict__ elist,
    float* __restrict__ out)
{
    const int tid  = threadIdx.x;
    const int lane = tid & 63;
    const int w    = tid >> 6;
    const int b    = blockIdx.x;          // 12288 blocks
    const int xcd  = b & 7;
    const int li   = b >> 3;              // 0..1535
    const int pr   = xcd*3 + (li >> 9);   // bt pair 0..23
    const int node = ((li & 511) << 2) | w;
    const int sub  = lane >> 4;
    const int fq   = lane & 15;
    const int bt0  = pr*2;
    const size_t S = (size_t)NN*FF;

    const uint2 ku0 = *(const uint2*)(Kh + ((size_t)bt0*NN + node)*32 + 2*fq);
    const uint2 ku1 = *(const uint2*)(Kh + ((size_t)(bt0+1)*NN + node)*32 + 2*fq);
    const half2v k01a = h2(ku0.x), k23a = h2(ku0.y);
    const half2v k01b = h2(ku1.x), k23b = h2(ku1.y);
    const half2v c001 = half2v{(_Float16)0.01f, (_Float16)0.01f};
    const half2v one2 = half2v{(_Float16)1.f, (_Float16)1.f};
    const half2v zero2 = half2v{(_Float16)0.f, (_Float16)0.f};
    const unsigned* QV0 = QV + (size_t)bt0*S;
    const unsigned* QV1 = QV0 + S;

    half2v a01_0 = zero2, a23_0 = zero2;  // bt0
    half2v a01_1 = zero2, a23_1 = zero2;  // bt1
    const int s0 = offs[node], s1 = offs[node+1];

    for (int i = s0; i < s1; i += 16){
        const int rem  = s1 - i;          // wave-uniform
        const int4 ev = *(const int4*)(elist + i + 4*sub);
        const unsigned o0 = (((unsigned)ev.x)<<6) + (fq<<2);
        const unsigned o1 = (((unsigned)ev.y)<<6) + (fq<<2);
        const unsigned o2 = (((unsigned)ev.z)<<6) + (fq<<2);
        const unsigned o3 = (((unsigned)ev.w)<<6) + (fq<<2);
        const uint4 u00 = *(const uint4*)(QV0 + o0);
        const uint4 u10 = *(const uint4*)(QV1 + o0);
        const uint4 u01 = *(const uint4*)(QV0 + o1);
        const uint4 u11 = *(const uint4*)(QV1 + o1);
        const uint4 u02 = *(const uint4*)(QV0 + o2);
        const uint4 u12 = *(const uint4*)(QV1 + o2);
        const uint4 u03 = *(const uint4*)(QV0 + o3);
        const uint4 u13 = *(const uint4*)(QV1 + o3);
        if (rem >= 16){
            HEDGE2(u00, k01a, k23a, a01_0, a23_0); HEDGE2(u10, k01b, k23b, a01_1, a23_1);
            HEDGE2(u01, k01a, k23a, a01_0, a23_0); HEDGE2(u11, k01b, k23b, a01_1, a23_1);
            HEDGE2(u02, k01a, k23a, a01_0, a23_0); HEDGE2(u12, k01b, k23b, a01_1, a23_1);
            HEDGE2(u03, k01a, k23a, a01_0, a23_0); HEDGE2(u13, k01b, k23b, a01_1, a23_1);
        } else {
            const half2v m0 = (4*sub+0 < rem) ? one2 : zero2;
            const half2v m1 = (4*sub+1 < rem) ? one2 : zero2;
            const half2v m2 = (4*sub+2 < rem) ? one2 : zero2;
            const half2v m3 = (4*sub+3 < rem) ? one2 : zero2;
            HEDGE2M(u00, k01a, k23a, a01_0, a23_0, m0); HEDGE2M(u10, k01b, k23b, a01_1, a23_1, m0);
            HEDGE2M(u01, k01a, k23a, a01_0, a23_0, m1); HEDGE2M(u11, k01b, k23b, a01_1, a23_1, m1);
            HEDGE2M(u02, k01a, k23a, a01_0, a23_0, m2); HEDGE2M(u12, k01b, k23b, a01_1, a23_1, m2);
            HEDGE2M(u03, k01a, k23a, a01_0, a23_0, m3); HEDGE2M(u13, k01b, k23b, a01_1, a23_1, m3);
        }
    }

    float4 ac0 = make_float4((float)a01_0[0], (float)a01_0[1],
                             (float)a23_0[0], (float)a23_0[1]);
    float4 ac1 = make_float4((float)a01_1[0], (float)a01_1[1],
                             (float)a23_1[0], (float)a23_1[1]);

    ac0.x += __shfl_xor(ac0.x, 16, 64); ac0.y += __shfl_xor(ac0.y, 16, 64);
    ac0.z += __shfl_xor(ac0.z, 16, 64); ac0.w += __shfl_xor(ac0.w, 16, 64);
    ac0.x += __shfl_xor(ac0.x, 32, 64); ac0.y += __shfl_xor(ac0.y, 32, 64);
    ac0.z += __shfl_xor(ac0.z, 32, 64); ac0.w += __shfl_xor(ac0.w, 32, 64);
    ac1.x += __shfl_xor(ac1.x, 16, 64); ac1.y += __shfl_xor(ac1.y, 16, 64);
    ac1.z += __shfl_xor(ac1.z, 16, 64); ac1.w += __shfl_xor(ac1.w, 16, 64);
    ac1.x += __shfl_xor(ac1.x, 32, 64); ac1.y += __shfl_xor(ac1.y, 32, 64);
    ac1.z += __shfl_xor(ac1.z, 32, 64); ac1.w += __shfl_xor(ac1.w, 32, 64);

    if (sub == 0){
        const size_t r0 = ((size_t)bt0*NN + node)*FF;
        const size_t r1 = r0 + S;
        const float4 sk0 = *(const float4*)(out + r0 + fq*4);
        const float4 sk1 = *(const float4*)(out + r1 + fq*4);
        *(float4*)(out + r0 + fq*4) =
            make_float4(ac0.x+sk0.x, ac0.y+sk0.y, ac0.z+sk0.z, ac0.w+sk0.w);
        *(float4*)(out + r1 + fq*4) =
            make_float4(ac1.x+sk1.x, ac1.y+sk1.y, ac1.z+sk1.z, ac1.w+sk1.w);
    }
}

extern "C" void kernel_launch(void* const* d_in, const int* in_sizes, int n_in,
                              void* d_out, int out_size, void* d_ws, size_t ws_size,
                              hipStream_t stream)
{
    const float* x  = (const float*)d_in[0];
    const unsigned int* ew = (const unsigned int*)d_in[1];
    const float* Wk = (const float*)d_in[2];
    const float* bk = (const float*)d_in[3];
    const float* Wq = (const float*)d_in[4];
    const float* bq = (const float*)d_in[5];
    const float* Wv = (const float*)d_in[6];
    const float* bv = (const float*)d_in[7];
    const float* Ws = (const float*)d_in[8];
    const float* bs = (const float*)d_in[9];
    float* out = (float*)d_out;

    const size_t n = (size_t)ROWS*FF;
    unsigned* Kh = (unsigned*)d_ws;       // ROWS*32 u32
    unsigned* QV = Kh + (size_t)ROWS*32;  // ROWS*64 u32
    unsigned* Wp = QV + n;                // 8192 u32
    int* meta  = (int*)(Wp + 8192);
    int* flag  = meta;
    int* bar   = meta + 4;
    int* deg   = meta + 16;
    int* offs  = deg + NN;
    int* cur   = offs + NN + 16;
    int* elist = cur + NN;

    hipLaunchKernelGGL(wpack_kernel, dim3(1), dim3(256), 0, stream,
                       Wk, Wq, Wv, Ws, Wp, meta);
    hipLaunchKernelGGL(proj_kernel, dim3(ROWS/128), dim3(256), 0, stream,
                       x, Wp, bk, bq, bv, bs, Kh, QV, out);
    hipLaunchKernelGGL(csr_kernel, dim3(64), dim3(256), 0, stream,
                       ew, flag, bar, deg, offs, cur, elist);
    hipLaunchKernelGGL(agg_kernel, dim3(ROWS/8), dim3(256), 0, stream,
                       Kh, QV, offs, elist, out);
}

// Round 13
// 93.369 us; speedup vs baseline: 5.5776x; 1.0235x over previous
//
#include <hip/hip_runtime.h>

#define BT 48
#define NN 2048
#define FF 64
#define EE 32768
#define ROWS (BT*NN)          // 98304
#define PROJ_BLKS 768         // 128 rows each
#define CSR_BLKS 64

typedef __attribute__((ext_vector_type(2))) _Float16 half2v;
typedef __attribute__((ext_vector_type(8))) _Float16 half8v;
typedef __attribute__((ext_vector_type(4))) float float4v;

__device__ __forceinline__ unsigned cvt2h(float lo, float hi){
    union { half2v h; unsigned u; } c;
    c.h = half2v{(_Float16)lo, (_Float16)hi};
    return c.u;
}
__device__ __forceinline__ half2v h2(unsigned u){
    union { unsigned u; half2v h; } c; c.u = u; return c.h;
}

union FragH { unsigned u[4]; half8v h; uint4 u4; };

// ---------------- Kernel 0: W fragment pre-pack (+ meta zero) ----------
__global__ __launch_bounds__(256) void wpack_kernel(
    const float* __restrict__ Wk, const float* __restrict__ Wq,
    const float* __restrict__ Wv, const float* __restrict__ Ws,
    unsigned* __restrict__ Wp, int* __restrict__ meta)
{
    const int t = threadIdx.x;
    if (t < 8) meta[t] = 0;
    for (int idx = t; idx < 8192; idx += 256){
        const int mat = idx >> 11;
        const int r   = idx & 2047;
        const int ft  = r >> 9;
        const int h   = (r >> 8) & 1;
        const int l   = (r >> 2) & 63;
        const int jj  = r & 3;
        const float* W = (mat==0)?Wk:(mat==1)?Wq:(mat==2)?Wv:Ws;
        const int k0 = h*32 + (l>>4)*8 + 2*jj;
        const int c  = ft*16 + (l&15);
        Wp[idx] = cvt2h(W[(size_t)k0*FF + c], W[(size_t)(k0+1)*FF + c]);
    }
}

// ---------------- Kernel 1: proj (blocks 0..767) + CSR (768..831) -------
// proj: 4 waves, wm=w&1: 0 -> (K,skip), 1 -> (Q,V). Swapped MFMA
// (A=W, B=x): D[feature][xrow]; lane-local fp16 packing; QV store is one
// dwordx4 {q01,v01,q23,v23}. CSR blocks have no dependence on proj ->
// their ~10us hides under proj. gbar: csr blocks only wait on each other;
// proj blocks always retire -> no deadlock (832 blocks, capacity >1200).
__device__ __forceinline__ void gbar(int* ctr, int nblk){
    __syncthreads();
    if (threadIdx.x == 0){
        __threadfence();
        atomicAdd(ctr, 1);
        while (__hip_atomic_load(ctr, __ATOMIC_ACQUIRE, __HIP_MEMORY_SCOPE_AGENT) < nblk) {}
    }
    __syncthreads();
}

__global__ __launch_bounds__(256) void projcsr_kernel(
    const float* __restrict__ x, const unsigned* __restrict__ Wp,
    const float* __restrict__ bk, const float* __restrict__ bq,
    const float* __restrict__ bv, const float* __restrict__ bs,
    unsigned* __restrict__ Kh, unsigned* __restrict__ QV,
    float* __restrict__ out,
    const unsigned int* __restrict__ ew,
    int* __restrict__ flag, int* __restrict__ bar,
    int* __restrict__ deg, int* __restrict__ offs,
    int* __restrict__ cur, int* __restrict__ elist)
{
    if (blockIdx.x >= PROJ_BLKS){
        // ---------------- CSR part ----------------
        const int t = threadIdx.x;
        const int gtid = (blockIdx.x - PROJ_BLKS)*256 + t;   // 16384 threads

        for (int i=gtid; i<NN; i+=16384) deg[i] = 0;
        if (gtid < 16) elist[EE + gtid] = 0;
        unsigned f = 0;
        for (int i=gtid; i<8192; i+=16384) f |= ew[2*i+1];
        if (f) atomicOr((unsigned int*)flag, f);
        gbar(bar+0, CSR_BLKS);
        const bool i64 = (*flag == 0);

        for (int e=gtid; e<EE; e+=16384){
            const int d = i64 ? (int)ew[2*(EE+e)] : (int)ew[EE+e];
            atomicAdd(&deg[d], 1);
        }
        gbar(bar+1, CSR_BLKS);

        if (blockIdx.x == PROJ_BLKS){
            __shared__ int wsums[4];
            const int base = t*8;
            int v[8], pre[8];
            #pragma unroll
            for (int j=0;j<8;j++) v[j] = deg[base+j];
            pre[0] = 0;
            #pragma unroll
            for (int j=1;j<8;j++) pre[j] = pre[j-1] + v[j-1];
            const int s = pre[7] + v[7];
            int inc = s;
            const int lane = t & 63, wid = t >> 6;
            #pragma unroll
            for (int d=1; d<64; d<<=1){ int tt = __shfl_up(inc, d, 64); if (lane>=d) inc += tt; }
            if (lane == 63) wsums[wid] = inc;
            __syncthreads();
            if (t == 0){ int a=0; for (int k2=0;k2<4;k2++){ int tt=wsums[k2]; wsums[k2]=a; a+=tt; } }
            __syncthreads();
            const int excl = wsums[wid] + (inc - s);
            #pragma unroll
            for (int j=0;j<8;j++){ offs[base+j] = excl + pre[j]; cur[base+j] = excl + pre[j]; }
            if (t == 255) offs[NN] = excl + s;
        }
        gbar(bar+2, CSR_BLKS);

        for (int e=gtid; e<EE; e+=16384){
            int d, s;
            if (i64){ d = (int)ew[2*(EE+e)]; s = (int)ew[2*e]; }
            else    { d = (int)ew[EE+e];     s = (int)ew[e];   }
            const int pos = atomicAdd(&cur[d], 1);
            elist[pos] = s;
        }
        return;
    }

    // ---------------- proj part ----------------
    const int tid = threadIdx.x;
    const int w  = tid >> 6;
    const int l  = tid & 63;
    const int lr = l & 15;
    const int lh = l >> 4;
    const int wm = w & 1;                 // 0: K+skip, 1: Q+V
    const int matA = wm ? 1 : 0;          // Q : K
    const int matB = wm ? 2 : 3;          // V : skip
    const float* bmA = wm ? bq : bk;
    const float* bmB = wm ? bv : bs;

    FragH afA[4][2], afB[4][2];
    #pragma unroll
    for (int ft=0;ft<4;ft++)
        #pragma unroll
        for (int h=0;h<2;h++){
            afA[ft][h].u4 = *(const uint4*)(Wp + ((matA*4+ft)*2+h)*256 + l*4);
            afB[ft][h].u4 = *(const uint4*)(Wp + ((matB*4+ft)*2+h)*256 + l*4);
        }
    float4 biasA[4], biasB[4];
    #pragma unroll
    for (int ft=0;ft<4;ft++){
        biasA[ft] = *(const float4*)(bmA + ft*16 + lh*4);
        biasB[ft] = *(const float4*)(bmB + ft*16 + lh*4);
    }

    const int row0 = blockIdx.x * 128 + (w>>1)*64;
    #pragma unroll 2
    for (int rt=0; rt<4; ++rt){
        const int r16 = row0 + rt*16;
        const float* xr = x + (size_t)(r16 + lr)*FF + lh*8;
        const float4 xa0 = *(const float4*)(xr);
        const float4 xa1 = *(const float4*)(xr + 4);
        const float4 xb0 = *(const float4*)(xr + 32);
        const float4 xb1 = *(const float4*)(xr + 36);
        FragH b0, b1;
        b0.u[0]=cvt2h(xa0.x,xa0.y); b0.u[1]=cvt2h(xa0.z,xa0.w);
        b0.u[2]=cvt2h(xa1.x,xa1.y); b0.u[3]=cvt2h(xa1.z,xa1.w);
        b1.u[0]=cvt2h(xb0.x,xb0.y); b1.u[1]=cvt2h(xb0.z,xb0.w);
        b1.u[2]=cvt2h(xb1.x,xb1.y); b1.u[3]=cvt2h(xb1.z,xb1.w);

        const size_t row = (size_t)(r16 + lr);
        #pragma unroll
        for (int ft=0;ft<4;ft++){
            float4v aA = float4v{biasA[ft].x, biasA[ft].y, biasA[ft].z, biasA[ft].w};
            aA = __builtin_amdgcn_mfma_f32_16x16x32_f16(afA[ft][0].h, b0.h, aA, 0,0,0);
            aA = __builtin_amdgcn_mfma_f32_16x16x32_f16(afA[ft][1].h, b1.h, aA, 0,0,0);
            float4v aB = float4v{biasB[ft].x, biasB[ft].y, biasB[ft].z, biasB[ft].w};
            aB = __builtin_amdgcn_mfma_f32_16x16x32_f16(afB[ft][0].h, b0.h, aB, 0,0,0);
            aB = __builtin_amdgcn_mfma_f32_16x16x32_f16(afB[ft][1].h, b1.h, aB, 0,0,0);
            if (wm == 0){
                uint2 st; st.x = cvt2h(aA[0],aA[1]); st.y = cvt2h(aA[2],aA[3]);
                *(uint2*)(Kh + row*32 + ft*8 + lh*2) = st;
                *(float4*)(out + row*FF + ft*16 + lh*4) =
                    make_float4(aB[0],aB[1],aB[2],aB[3]);
            } else {
                uint4 st;
                st.x = cvt2h(aA[0],aA[1]); st.y = cvt2h(aB[0],aB[1]);
                st.z = cvt2h(aA[2],aA[3]); st.w = cvt2h(aB[2],aB[3]);
                *(uint4*)(QV + row*FF + ft*16 + lh*4) = st;
            }
        }
    }
}

// ---------------- Kernel 2: gather + gate + aggregate (fp16, 2 bt/wave) --
#define HEDGE2(U, KA, KB, A01, A23) { \
    half2v g01 = (KA) + h2((U).x); \
    g01 = __builtin_elementwise_max(g01, g01*c001); \
    (A01) += g01 * h2((U).y); \
    half2v g23 = (KB) + h2((U).z); \
    g23 = __builtin_elementwise_max(g23, g23*c001); \
    (A23) += g23 * h2((U).w); }
#define HEDGE2M(U, KA, KB, A01, A23, M) { \
    half2v g01 = (KA) + h2((U).x); \
    g01 = __builtin_elementwise_max(g01, g01*c001); \
    (A01) += g01 * (h2((U).y) * (M)); \
    half2v g23 = (KB) + h2((U).z); \
    g23 = __builtin_elementwise_max(g23, g23*c001); \
    (A23) += g23 * (h2((U).w) * (M)); }

__global__ __launch_bounds__(256) void agg_kernel(
    const unsigned* __restrict__ Kh, const unsigned* __restrict__ QV,
    const int* __restrict__ offs, const int* __restrict__ elist,
    float* __restrict__ out)
{
    const int tid  = threadIdx.x;
    const int lane = tid & 63;
    const int w    = tid >> 6;
    const int b    = blockIdx.x;          // 12288 blocks
    const int xcd  = b & 7;
    const int li   = b >> 3;              // 0..1535
    const int pr   = xcd*3 + (li >> 9);   // bt pair 0..23
    const int node = ((li & 511) << 2) | w;
    const int sub  = lane >> 4;
    const int fq   = lane & 15;
    const int bt0  = pr*2;
    const size_t S = (size_t)NN*FF;

    const uint2 ku0 = *(const uint2*)(Kh + ((size_t)bt0*NN + node)*32 + 2*fq);
    const uint2 ku1 = *(const uint2*)(Kh + ((size_t)(bt0+1)*NN + node)*32 + 2*fq);
    // hoist skip/out rows: overlap their latency with the edge loop
    const size_t r0 = ((size_t)bt0*NN + node)*FF;
    const size_t r1 = r0 + S;
    const float4 sk0 = *(const float4*)(out + r0 + fq*4);
    const float4 sk1 = *(const float4*)(out + r1 + fq*4);

    const half2v k01a = h2(ku0.x), k23a = h2(ku0.y);
    const half2v k01b = h2(ku1.x), k23b = h2(ku1.y);
    const half2v c001 = half2v{(_Float16)0.01f, (_Float16)0.01f};
    const half2v one2 = half2v{(_Float16)1.f, (_Float16)1.f};
    const half2v zero2 = half2v{(_Float16)0.f, (_Float16)0.f};
    const unsigned* QV0 = QV + (size_t)bt0*S;
    const unsigned* QV1 = QV0 + S;

    half2v a01_0 = zero2, a23_0 = zero2;  // bt0
    half2v a01_1 = zero2, a23_1 = zero2;  // bt1
    const int s0 = offs[node], s1 = offs[node+1];

    for (int i = s0; i < s1; i += 16){
        const int rem  = s1 - i;          // wave-uniform
        const int4 ev = *(const int4*)(elist + i + 4*sub);
        const unsigned o0 = (((unsigned)ev.x)<<6) + (fq<<2);
        const unsigned o1 = (((unsigned)ev.y)<<6) + (fq<<2);
        const unsigned o2 = (((unsigned)ev.z)<<6) + (fq<<2);
        const unsigned o3 = (((unsigned)ev.w)<<6) + (fq<<2);
        const uint4 u00 = *(const uint4*)(QV0 + o0);
        const uint4 u10 = *(const uint4*)(QV1 + o0);
        const uint4 u01 = *(const uint4*)(QV0 + o1);
        const uint4 u11 = *(const uint4*)(QV1 + o1);
        const uint4 u02 = *(const uint4*)(QV0 + o2);
        const uint4 u12 = *(const uint4*)(QV1 + o2);
        const uint4 u03 = *(const uint4*)(QV0 + o3);
        const uint4 u13 = *(const uint4*)(QV1 + o3);
        if (rem >= 16){
            HEDGE2(u00, k01a, k23a, a01_0, a23_0); HEDGE2(u10, k01b, k23b, a01_1, a23_1);
            HEDGE2(u01, k01a, k23a, a01_0, a23_0); HEDGE2(u11, k01b, k23b, a01_1, a23_1);
            HEDGE2(u02, k01a, k23a, a01_0, a23_0); HEDGE2(u12, k01b, k23b, a01_1, a23_1);
            HEDGE2(u03, k01a, k23a, a01_0, a23_0); HEDGE2(u13, k01b, k23b, a01_1, a23_1);
        } else {
            const half2v m0 = (4*sub+0 < rem) ? one2 : zero2;
            const half2v m1 = (4*sub+1 < rem) ? one2 : zero2;
            const half2v m2 = (4*sub+2 < rem) ? one2 : zero2;
            const half2v m3 = (4*sub+3 < rem) ? one2 : zero2;
            HEDGE2M(u00, k01a, k23a, a01_0, a23_0, m0); HEDGE2M(u10, k01b, k23b, a01_1, a23_1, m0);
            HEDGE2M(u01, k01a, k23a, a01_0, a23_0, m1); HEDGE2M(u11, k01b, k23b, a01_1, a23_1, m1);
            HEDGE2M(u02, k01a, k23a, a01_0, a23_0, m2); HEDGE2M(u12, k01b, k23b, a01_1, a23_1, m2);
            HEDGE2M(u03, k01a, k23a, a01_0, a23_0, m3); HEDGE2M(u13, k01b, k23b, a01_1, a23_1, m3);
        }
    }

    float4 ac0 = make_float4((float)a01_0[0], (float)a01_0[1],
                             (float)a23_0[0], (float)a23_0[1]);
    float4 ac1 = make_float4((float)a01_1[0], (float)a01_1[1],
                             (float)a23_1[0], (float)a23_1[1]);

    ac0.x += __shfl_xor(ac0.x, 16, 64); ac0.y += __shfl_xor(ac0.y, 16, 64);
    ac0.z += __shfl_xor(ac0.z, 16, 64); ac0.w += __shfl_xor(ac0.w, 16, 64);
    ac0.x += __shfl_xor(ac0.x, 32, 64); ac0.y += __shfl_xor(ac0.y, 32, 64);
    ac0.z += __shfl_xor(ac0.z, 32, 64); ac0.w += __shfl_xor(ac0.w, 32, 64);
    ac1.x += __shfl_xor(ac1.x, 16, 64); ac1.y += __shfl_xor(ac1.y, 16, 64);
    ac1.z += __shfl_xor(ac1.z, 16, 64); ac1.w += __shfl_xor(ac1.w, 16, 64);
    ac1.x += __shfl_xor(ac1.x, 32, 64); ac1.y += __shfl_xor(ac1.y, 32, 64);
    ac1.z += __shfl_xor(ac1.z, 32, 64); ac1.w += __shfl_xor(ac1.w, 32, 64);

    if (sub == 0){
        *(float4*)(out + r0 + fq*4) =
            make_float4(ac0.x+sk0.x, ac0.y+sk0.y, ac0.z+sk0.z, ac0.w+sk0.w);
        *(float4*)(out + r1 + fq*4) =
            make_float4(ac1.x+sk1.x, ac1.y+sk1.y, ac1.z+sk1.z, ac1.w+sk1.w);
    }
}

extern "C" void kernel_launch(void* const* d_in, const int* in_sizes, int n_in,
                              void* d_out, int out_size, void* d_ws, size_t ws_size,
                              hipStream_t stream)
{
    const float* x  = (const float*)d_in[0];
    const unsigned int* ew = (const unsigned int*)d_in[1];
    const float* Wk = (const float*)d_in[2];
    const float* bk = (const float*)d_in[3];
    const float* Wq = (const float*)d_in[4];
    const float* bq = (const float*)d_in[5];
    const float* Wv = (const float*)d_in[6];
    const float* bv = (const float*)d_in[7];
    const float* Ws = (const float*)d_in[8];
    const float* bs = (const float*)d_in[9];
    float* out = (float*)d_out;

    const size_t n = (size_t)ROWS*FF;
    unsigned* Kh = (unsigned*)d_ws;       // ROWS*32 u32
    unsigned* QV = Kh + (size_t)ROWS*32;  // ROWS*64 u32
    unsigned* Wp = QV + n;                // 8192 u32
    int* meta  = (int*)(Wp + 8192);
    int* flag  = meta;
    int* bar   = meta + 4;
    int* deg   = meta + 16;
    int* offs  = deg + NN;
    int* cur   = offs + NN + 16;
    int* elist = cur + NN;

    hipLaunchKernelGGL(wpack_kernel, dim3(1), dim3(256), 0, stream,
                       Wk, Wq, Wv, Ws, Wp, meta);
    hipLaunchKernelGGL(projcsr_kernel, dim3(PROJ_BLKS + CSR_BLKS), dim3(256), 0, stream,
                       x, Wp, bk, bq, bv, bs, Kh, QV, out,
                       ew, flag, bar, deg, offs, cur, elist);
    hipLaunchKernelGGL(agg_kernel, dim3(ROWS/8), dim3(256), 0, stream,
                       Kh, QV, offs, elist, out);
}

// Round 14
// 92.289 us; speedup vs baseline: 5.6429x; 1.0117x over previous
//
#include <hip/hip_runtime.h>

#define BT 48
#define NN 2048
#define FF 64
#define EE 32768
#define ROWS (BT*NN)          // 98304
#define PROJ_BLKS 768         // 128 rows each
#define CSR_BLKS 64
#define XPITCH 68             // LDS row pitch (floats): breaks 256B-stride bank conflicts

typedef __attribute__((ext_vector_type(2))) _Float16 half2v;
typedef __attribute__((ext_vector_type(8))) _Float16 half8v;
typedef __attribute__((ext_vector_type(4))) float float4v;

__device__ __forceinline__ unsigned cvt2h(float lo, float hi){
    union { half2v h; unsigned u; } c;
    c.h = half2v{(_Float16)lo, (_Float16)hi};
    return c.u;
}
__device__ __forceinline__ half2v h2(unsigned u){
    union { unsigned u; half2v h; } c; c.u = u; return c.h;
}

union FragH { unsigned u[4]; half8v h; uint4 u4; };

// ---------------- Kernel 0: W fragment pre-pack (+ meta zero) ----------
__global__ __launch_bounds__(256) void wpack_kernel(
    const float* __restrict__ Wk, const float* __restrict__ Wq,
    const float* __restrict__ Wv, const float* __restrict__ Ws,
    unsigned* __restrict__ Wp, int* __restrict__ meta)
{
    const int t = threadIdx.x;
    if (t < 8) meta[t] = 0;
    for (int idx = t; idx < 8192; idx += 256){
        const int mat = idx >> 11;
        const int r   = idx & 2047;
        const int ft  = r >> 9;
        const int h   = (r >> 8) & 1;
        const int l   = (r >> 2) & 63;
        const int jj  = r & 3;
        const float* W = (mat==0)?Wk:(mat==1)?Wq:(mat==2)?Wv:Ws;
        const int k0 = h*32 + (l>>4)*8 + 2*jj;
        const int c  = ft*16 + (l&15);
        Wp[idx] = cvt2h(W[(size_t)k0*FF + c], W[(size_t)(k0+1)*FF + c]);
    }
}

// ---------------- Kernel 1: proj (blocks 0..767) + CSR (768..831) -------
// proj: x staged in LDS (coalesced float4; pitch 68 floats -> 2-way-free
// bank access on the 256B-stride fragment reads). W frags from Wp (64
// VGPRs); __launch_bounds__(256,4) caps at 128 VGPR so the compiler has
// ~30 free regs to pipeline ds_read/cvt/MFMA/stores (R13's VGPR=72 left
// ZERO free -> every load serialized at full memory latency).
// CSR blocks (no proj dependence) hide under proj; gbar only among csr.
__device__ __forceinline__ void gbar(int* ctr, int nblk){
    __syncthreads();
    if (threadIdx.x == 0){
        __threadfence();
        atomicAdd(ctr, 1);
        while (__hip_atomic_load(ctr, __ATOMIC_ACQUIRE, __HIP_MEMORY_SCOPE_AGENT) < nblk) {}
    }
    __syncthreads();
}

__global__ __launch_bounds__(256, 4) void projcsr_kernel(
    const float* __restrict__ x, const unsigned* __restrict__ Wp,
    const float* __restrict__ bk, const float* __restrict__ bq,
    const float* __restrict__ bv, const float* __restrict__ bs,
    unsigned* __restrict__ Kh, unsigned* __restrict__ QV,
    float* __restrict__ out,
    const unsigned int* __restrict__ ew,
    int* __restrict__ flag, int* __restrict__ bar,
    int* __restrict__ deg, int* __restrict__ offs,
    int* __restrict__ cur, int* __restrict__ elist)
{
    __shared__ float xs[128*XPITCH];      // 34 KB
    __shared__ int wsums[4];

    if (blockIdx.x >= PROJ_BLKS){
        // ---------------- CSR part ----------------
        const int t = threadIdx.x;
        const int gtid = (blockIdx.x - PROJ_BLKS)*256 + t;   // 16384 threads

        for (int i=gtid; i<NN; i+=16384) deg[i] = 0;
        if (gtid < 16) elist[EE + gtid] = 0;
        unsigned f = 0;
        for (int i=gtid; i<8192; i+=16384) f |= ew[2*i+1];
        if (f) atomicOr((unsigned int*)flag, f);
        gbar(bar+0, CSR_BLKS);
        const bool i64 = (*flag == 0);

        for (int e=gtid; e<EE; e+=16384){
            const int d = i64 ? (int)ew[2*(EE+e)] : (int)ew[EE+e];
            atomicAdd(&deg[d], 1);
        }
        gbar(bar+1, CSR_BLKS);

        if (blockIdx.x == PROJ_BLKS){
            const int base = t*8;
            int v[8], pre[8];
            #pragma unroll
            for (int j=0;j<8;j++) v[j] = deg[base+j];
            pre[0] = 0;
            #pragma unroll
            for (int j=1;j<8;j++) pre[j] = pre[j-1] + v[j-1];
            const int s = pre[7] + v[7];
            int inc = s;
            const int lane = t & 63, wid = t >> 6;
            #pragma unroll
            for (int d=1; d<64; d<<=1){ int tt = __shfl_up(inc, d, 64); if (lane>=d) inc += tt; }
            if (lane == 63) wsums[wid] = inc;
            __syncthreads();
            if (t == 0){ int a=0; for (int k2=0;k2<4;k2++){ int tt=wsums[k2]; wsums[k2]=a; a+=tt; } }
            __syncthreads();
            const int excl = wsums[wid] + (inc - s);
            #pragma unroll
            for (int j=0;j<8;j++){ offs[base+j] = excl + pre[j]; cur[base+j] = excl + pre[j]; }
            if (t == 255) offs[NN] = excl + s;
        }
        gbar(bar+2, CSR_BLKS);

        for (int e=gtid; e<EE; e+=16384){
            int d, s;
            if (i64){ d = (int)ew[2*(EE+e)]; s = (int)ew[2*e]; }
            else    { d = (int)ew[EE+e];     s = (int)ew[e];   }
            const int pos = atomicAdd(&cur[d], 1);
            elist[pos] = s;
        }
        return;
    }

    // ---------------- proj part ----------------
    const int tid = threadIdx.x;
    const int w  = tid >> 6;
    const int l  = tid & 63;
    const int lr = l & 15;
    const int lh = l >> 4;
    const int wm = w & 1;                 // 0: K+skip, 1: Q+V
    const int matA = wm ? 1 : 0;          // Q : K
    const int matB = wm ? 2 : 3;          // V : skip
    const float* bmA = wm ? bq : bk;
    const float* bmB = wm ? bv : bs;

    // stage 128 rows of x into LDS (coalesced)
    {
        const float4* xg = (const float4*)(x + (size_t)blockIdx.x*128*FF);
        for (int i = tid; i < 128*16; i += 256){
            const int row = i >> 4, c4 = i & 15;
            *(float4*)(xs + row*XPITCH + c4*4) = xg[i];
        }
    }

    FragH afA[4][2], afB[4][2];
    #pragma unroll
    for (int ft=0;ft<4;ft++)
        #pragma unroll
        for (int h=0;h<2;h++){
            afA[ft][h].u4 = *(const uint4*)(Wp + ((matA*4+ft)*2+h)*256 + l*4);
            afB[ft][h].u4 = *(const uint4*)(Wp + ((matB*4+ft)*2+h)*256 + l*4);
        }
    float4 biasA[4], biasB[4];
    #pragma unroll
    for (int ft=0;ft<4;ft++){
        biasA[ft] = *(const float4*)(bmA + ft*16 + lh*4);
        biasB[ft] = *(const float4*)(bmB + ft*16 + lh*4);
    }
    __syncthreads();

    const int lrow0 = (w>>1)*64;
    #pragma unroll 2
    for (int rt=0; rt<4; ++rt){
        const int lrow = lrow0 + rt*16 + lr;
        const float* xr = xs + lrow*XPITCH + lh*8;
        const float4 xa0 = *(const float4*)(xr);
        const float4 xa1 = *(const float4*)(xr + 4);
        const float4 xb0 = *(const float4*)(xr + 32);
        const float4 xb1 = *(const float4*)(xr + 36);
        FragH b0, b1;
        b0.u[0]=cvt2h(xa0.x,xa0.y); b0.u[1]=cvt2h(xa0.z,xa0.w);
        b0.u[2]=cvt2h(xa1.x,xa1.y); b0.u[3]=cvt2h(xa1.z,xa1.w);
        b1.u[0]=cvt2h(xb0.x,xb0.y); b1.u[1]=cvt2h(xb0.z,xb0.w);
        b1.u[2]=cvt2h(xb1.x,xb1.y); b1.u[3]=cvt2h(xb1.z,xb1.w);

        const size_t row = (size_t)blockIdx.x*128 + lrow;
        #pragma unroll
        for (int ft=0;ft<4;ft++){
            float4v aA = float4v{biasA[ft].x, biasA[ft].y, biasA[ft].z, biasA[ft].w};
            aA = __builtin_amdgcn_mfma_f32_16x16x32_f16(afA[ft][0].h, b0.h, aA, 0,0,0);
            aA = __builtin_amdgcn_mfma_f32_16x16x32_f16(afA[ft][1].h, b1.h, aA, 0,0,0);
            float4v aB = float4v{biasB[ft].x, biasB[ft].y, biasB[ft].z, biasB[ft].w};
            aB = __builtin_amdgcn_mfma_f32_16x16x32_f16(afB[ft][0].h, b0.h, aB, 0,0,0);
            aB = __builtin_amdgcn_mfma_f32_16x16x32_f16(afB[ft][1].h, b1.h, aB, 0,0,0);
            if (wm == 0){
                uint2 st; st.x = cvt2h(aA[0],aA[1]); st.y = cvt2h(aA[2],aA[3]);
                *(uint2*)(Kh + row*32 + ft*8 + lh*2) = st;
                *(float4*)(out + row*FF + ft*16 + lh*4) =
                    make_float4(aB[0],aB[1],aB[2],aB[3]);
            } else {
                uint4 st;
                st.x = cvt2h(aA[0],aA[1]); st.y = cvt2h(aB[0],aB[1]);
                st.z = cvt2h(aA[2],aA[3]); st.w = cvt2h(aB[2],aB[3]);
                *(uint4*)(QV + row*FF + ft*16 + lh*4) = st;
            }
        }
    }
}

// ---------------- Kernel 2: gather + gate + aggregate (fp16, 2 bt/wave) --
#define HEDGE2(U, KA, KB, A01, A23) { \
    half2v g01 = (KA) + h2((U).x); \
    g01 = __builtin_elementwise_max(g01, g01*c001); \
    (A01) += g01 * h2((U).y); \
    half2v g23 = (KB) + h2((U).z); \
    g23 = __builtin_elementwise_max(g23, g23*c001); \
    (A23) += g23 * h2((U).w); }
#define HEDGE2M(U, KA, KB, A01, A23, M) { \
    half2v g01 = (KA) + h2((U).x); \
    g01 = __builtin_elementwise_max(g01, g01*c001); \
    (A01) += g01 * (h2((U).y) * (M)); \
    half2v g23 = (KB) + h2((U).z); \
    g23 = __builtin_elementwise_max(g23, g23*c001); \
    (A23) += g23 * (h2((U).w) * (M)); }

__global__ __launch_bounds__(256) void agg_kernel(
    const unsigned* __restrict__ Kh, const unsigned* __restrict__ QV,
    const int* __restrict__ offs, const int* __restrict__ elist,
    float* __restrict__ out)
{
    const int tid  = threadIdx.x;
    const int lane = tid & 63;
    const int w    = tid >> 6;
    const int b    = blockIdx.x;          // 12288 blocks
    const int xcd  = b & 7;
    const int li   = b >> 3;              // 0..1535
    const int pr   = xcd*3 + (li >> 9);   // bt pair 0..23
    const int node = ((li & 511) << 2) | w;
    const int sub  = lane >> 4;
    const int fq   = lane & 15;
    const int bt0  = pr*2;
    const size_t S = (size_t)NN*FF;

    const uint2 ku0 = *(const uint2*)(Kh + ((size_t)bt0*NN + node)*32 + 2*fq);
    const uint2 ku1 = *(const uint2*)(Kh + ((size_t)(bt0+1)*NN + node)*32 + 2*fq);
    const size_t r0 = ((size_t)bt0*NN + node)*FF;
    const size_t r1 = r0 + S;
    const float4 sk0 = *(const float4*)(out + r0 + fq*4);
    const float4 sk1 = *(const float4*)(out + r1 + fq*4);

    const half2v k01a = h2(ku0.x), k23a = h2(ku0.y);
    const half2v k01b = h2(ku1.x), k23b = h2(ku1.y);
    const half2v c001 = half2v{(_Float16)0.01f, (_Float16)0.01f};
    const half2v one2 = half2v{(_Float16)1.f, (_Float16)1.f};
    const half2v zero2 = half2v{(_Float16)0.f, (_Float16)0.f};
    const unsigned* QV0 = QV + (size_t)bt0*S;
    const unsigned* QV1 = QV0 + S;

    half2v a01_0 = zero2, a23_0 = zero2;  // bt0
    half2v a01_1 = zero2, a23_1 = zero2;  // bt1
    const int s0 = offs[node], s1 = offs[node+1];

    for (int i = s0; i < s1; i += 16){
        const int rem  = s1 - i;          // wave-uniform
        const int4 ev = *(const int4*)(elist + i + 4*sub);
        const unsigned o0 = (((unsigned)ev.x)<<6) + (fq<<2);
        const unsigned o1 = (((unsigned)ev.y)<<6) + (fq<<2);
        const unsigned o2 = (((unsigned)ev.z)<<6) + (fq<<2);
        const unsigned o3 = (((unsigned)ev.w)<<6) + (fq<<2);
        const uint4 u00 = *(const uint4*)(QV0 + o0);
        const uint4 u10 = *(const uint4*)(QV1 + o0);
        const uint4 u01 = *(const uint4*)(QV0 + o1);
        const uint4 u11 = *(const uint4*)(QV1 + o1);
        const uint4 u02 = *(const uint4*)(QV0 + o2);
        const uint4 u12 = *(const uint4*)(QV1 + o2);
        const uint4 u03 = *(const uint4*)(QV0 + o3);
        const uint4 u13 = *(const uint4*)(QV1 + o3);
        if (rem >= 16){
            HEDGE2(u00, k01a, k23a, a01_0, a23_0); HEDGE2(u10, k01b, k23b, a01_1, a23_1);
            HEDGE2(u01, k01a, k23a, a01_0, a23_0); HEDGE2(u11, k01b, k23b, a01_1, a23_1);
            HEDGE2(u02, k01a, k23a, a01_0, a23_0); HEDGE2(u12, k01b, k23b, a01_1, a23_1);
            HEDGE2(u03, k01a, k23a, a01_0, a23_0); HEDGE2(u13, k01b, k23b, a01_1, a23_1);
        } else {
            const half2v m0 = (4*sub+0 < rem) ? one2 : zero2;
            const half2v m1 = (4*sub+1 < rem) ? one2 : zero2;
            const half2v m2 = (4*sub+2 < rem) ? one2 : zero2;
            const half2v m3 = (4*sub+3 < rem) ? one2 : zero2;
            HEDGE2M(u00, k01a, k23a, a01_0, a23_0, m0); HEDGE2M(u10, k01b, k23b, a01_1, a23_1, m0);
            HEDGE2M(u01, k01a, k23a, a01_0, a23_0, m1); HEDGE2M(u11, k01b, k23b, a01_1, a23_1, m1);
            HEDGE2M(u02, k01a, k23a, a01_0, a23_0, m2); HEDGE2M(u12, k01b, k23b, a01_1, a23_1, m2);
            HEDGE2M(u03, k01a, k23a, a01_0, a23_0, m3); HEDGE2M(u13, k01b, k23b, a01_1, a23_1, m3);
        }
    }

    float4 ac0 = make_float4((float)a01_0[0], (float)a01_0[1],
                             (float)a23_0[0], (float)a23_0[1]);
    float4 ac1 = make_float4((float)a01_1[0], (float)a01_1[1],
                             (float)a23_1[0], (float)a23_1[1]);

    ac0.x += __shfl_xor(ac0.x, 16, 64); ac0.y += __shfl_xor(ac0.y, 16, 64);
    ac0.z += __shfl_xor(ac0.z, 16, 64); ac0.w += __shfl_xor(ac0.w, 16, 64);
    ac0.x += __shfl_xor(ac0.x, 32, 64); ac0.y += __shfl_xor(ac0.y, 32, 64);
    ac0.z += __shfl_xor(ac0.z, 32, 64); ac0.w += __shfl_xor(ac0.w, 32, 64);
    ac1.x += __shfl_xor(ac1.x, 16, 64); ac1.y += __shfl_xor(ac1.y, 16, 64);
    ac1.z += __shfl_xor(ac1.z, 16, 64); ac1.w += __shfl_xor(ac1.w, 16, 64);
    ac1.x += __shfl_xor(ac1.x, 32, 64); ac1.y += __shfl_xor(ac1.y, 32, 64);
    ac1.z += __shfl_xor(ac1.z, 32, 64); ac1.w += __shfl_xor(ac1.w, 32, 64);

    if (sub == 0){
        *(float4*)(out + r0 + fq*4) =
            make_float4(ac0.x+sk0.x, ac0.y+sk0.y, ac0.z+sk0.z, ac0.w+sk0.w);
        *(float4*)(out + r1 + fq*4) =
            make_float4(ac1.x+sk1.x, ac1.y+sk1.y, ac1.z+sk1.z, ac1.w+sk1.w);
    }
}

extern "C" void kernel_launch(void* const* d_in, const int* in_sizes, int n_in,
                              void* d_out, int out_size, void* d_ws, size_t ws_size,
                              hipStream_t stream)
{
    const float* x  = (const float*)d_in[0];
    const unsigned int* ew = (const unsigned int*)d_in[1];
    const float* Wk = (const float*)d_in[2];
    const float* bk = (const float*)d_in[3];
    const float* Wq = (const float*)d_in[4];
    const float* bq = (const float*)d_in[5];
    const float* Wv = (const float*)d_in[6];
    const float* bv = (const float*)d_in[7];
    const float* Ws = (const float*)d_in[8];
    const float* bs = (const float*)d_in[9];
    float* out = (float*)d_out;

    const size_t n = (size_t)ROWS*FF;
    unsigned* Kh = (unsigned*)d_ws;       // ROWS*32 u32
    unsigned* QV = Kh + (size_t)ROWS*32;  // ROWS*64 u32
    unsigned* Wp = QV + n;                // 8192 u32
    int* meta  = (int*)(Wp + 8192);
    int* flag  = meta;
    int* bar   = meta + 4;
    int* deg   = meta + 16;
    int* offs  = deg + NN;
    int* cur   = offs + NN + 16;
    int* elist = cur + NN;

    hipLaunchKernelGGL(wpack_kernel, dim3(1), dim3(256), 0, stream,
                       Wk, Wq, Wv, Ws, Wp, meta);
    hipLaunchKernelGGL(projcsr_kernel, dim3(PROJ_BLKS + CSR_BLKS), dim3(256), 0, stream,
                       x, Wp, bk, bq, bv, bs, Kh, QV, out,
                       ew, flag, bar, deg, offs, cur, elist);
    hipLaunchKernelGGL(agg_kernel, dim3(ROWS/8), dim3(256), 0, stream,
                       Kh, QV, offs, elist, out);
}